// Round 13
// baseline (686.098 us; speedup 1.0000x reference)
//
#include <hip/hip_runtime.h>
#include <hip/hip_bf16.h>

// N=100000, E=1600000.
// R13: xw2pack inner GEMV vectorized -- shH/shW2 padded to 72 rows, 18x
// ds_read_b128 + 4 independent accumulator chains (was 70 scalar reads
// on one serial fma chain). Everything else unchanged from R12.

#define NEG_SLOPE 0.2f

__device__ __forceinline__ float bf_lo(unsigned u) { return __uint_as_float(u << 16); }
__device__ __forceinline__ float bf_hi(unsigned u) { return __uint_as_float(u & 0xffff0000u); }
__device__ __forceinline__ unsigned pk(float lo, float hi)
{
    __hip_bfloat16 l = __float2bfloat16(lo), h = __float2bfloat16(hi);
    unsigned ul = reinterpret_cast<unsigned short&>(l);
    unsigned uh = reinterpret_cast<unsigned short&>(h);
    return ul | (uh << 16);
}

// ---------------------------------------------------------------------------
// Encoder: 8 nodes/block, 32 lanes/node. K/V staged as bf16 (32B/token).
// ---------------------------------------------------------------------------
__global__ void __launch_bounds__(256) encoder_kernel(
    const float* __restrict__ Xf,
    const float* __restrict__ Wq, const float* __restrict__ bq,
    const float* __restrict__ Wk, const float* __restrict__ bk,
    const float* __restrict__ Wv, const float* __restrict__ bv,
    const float* __restrict__ g0, const float* __restrict__ be0,
    const float* __restrict__ Wf1, const float* __restrict__ bf1,
    const float* __restrict__ Wf2, const float* __restrict__ bf2,
    const float* __restrict__ g1, const float* __restrict__ be1,
    const float* __restrict__ Wrep, const float* __restrict__ brep,
    float* __restrict__ xt, int n)
{
    __shared__ float sh[2560];
    int t = threadIdx.x;
    int bid = blockIdx.x;
    size_t base = (size_t)bid * 2560;
#pragma unroll
    for (int i = 0; i < 10; ++i) sh[i * 256 + t] = Xf[base + i * 256 + t];
    __syncthreads();

    int sub = t >> 5;
    int s   = t & 31;
    int v   = bid * 8 + sub;

    float xv[10];
#pragma unroll
    for (int i = 0; i < 10; ++i) xv[i] = sh[sub * 320 + s * 10 + i];
    __syncthreads();   // Xf consumed; slab reused for bf16 K/V

    float q[6], k[6], w[6];
#pragma unroll
    for (int j = 0; j < 6; ++j) { q[j] = bq[j]; k[j] = bk[j]; w[j] = bv[j]; }
#pragma unroll
    for (int i = 0; i < 10; ++i) {
#pragma unroll
        for (int j = 0; j < 6; ++j) {
            q[j] += xv[i] * Wq[i * 6 + j];
            k[j] += xv[i] * Wk[i * 6 + j];
            w[j] += xv[i] * Wv[i * 6 + j];
        }
    }

    uint4* shu = (uint4*)sh;
    int nb = sub * 64;
    shu[nb + s * 2]     = make_uint4(pk(k[0], k[1]), pk(k[2], k[3]),
                                     pk(k[4], k[5]), pk(w[0], w[1]));
    shu[nb + s * 2 + 1] = make_uint4(pk(w[2], w[3]), pk(w[4], w[5]), 0u, 0u);
    __builtin_amdgcn_wave_barrier();

    const float scale = 0.40824829046386301637f;  // 1/sqrt(6)
    float q0s = q[0] * scale, q1s = q[1] * scale, q2s = q[2] * scale;
    float q3s = q[3] * scale, q4s = q[4] * scale, q5s = q[5] * scale;

    float dA0 = 0.f, dB0 = 0.f, dA1 = 0.f, dB1 = 0.f;
    float aA00 = 0.f, aA01 = 0.f, aA02 = 0.f;
    float aB00 = 0.f, aB01 = 0.f, aB02 = 0.f;
    float aA10 = 0.f, aA11 = 0.f, aA12 = 0.f;
    float aB10 = 0.f, aB11 = 0.f, aB12 = 0.f;

#pragma unroll 4
    for (int t2 = 0; t2 < 32; t2 += 2) {
        uint4 Ua = shu[nb + t2 * 2];
        uint4 Ub = shu[nb + t2 * 2 + 1];
        uint4 Uc = shu[nb + t2 * 2 + 2];
        uint4 Ud = shu[nb + t2 * 2 + 3];
        {
            float k0 = bf_lo(Ua.x), k1 = bf_hi(Ua.x);
            float k2 = bf_lo(Ua.y), k3 = bf_hi(Ua.y);
            float k4 = bf_lo(Ua.z), k5 = bf_hi(Ua.z);
            float v0 = bf_lo(Ua.w), v1 = bf_hi(Ua.w);
            float v2 = bf_lo(Ub.x), v3 = bf_hi(Ub.x);
            float v4 = bf_lo(Ub.y), v5 = bf_hi(Ub.y);
            float p0 = __expf(q0s * k0 + q1s * k1 + q2s * k2);
            float p1 = __expf(q3s * k3 + q4s * k4 + q5s * k5);
            dA0 += p0; aA00 += p0 * v0; aA01 += p0 * v1; aA02 += p0 * v2;
            dA1 += p1; aA10 += p1 * v3; aA11 += p1 * v4; aA12 += p1 * v5;
        }
        {
            float k0 = bf_lo(Uc.x), k1 = bf_hi(Uc.x);
            float k2 = bf_lo(Uc.y), k3 = bf_hi(Uc.y);
            float k4 = bf_lo(Uc.z), k5 = bf_hi(Uc.z);
            float v0 = bf_lo(Uc.w), v1 = bf_hi(Uc.w);
            float v2 = bf_lo(Ud.x), v3 = bf_hi(Ud.x);
            float v4 = bf_lo(Ud.y), v5 = bf_hi(Ud.y);
            float p0 = __expf(q0s * k0 + q1s * k1 + q2s * k2);
            float p1 = __expf(q3s * k3 + q4s * k4 + q5s * k5);
            dB0 += p0; aB00 += p0 * v0; aB01 += p0 * v1; aB02 += p0 * v2;
            dB1 += p1; aB10 += p1 * v3; aB11 += p1 * v4; aB12 += p1 * v5;
        }
    }

    float O[6];
    {
        float inv0 = 1.f / (dA0 + dB0);
        float inv1 = 1.f / (dA1 + dB1);
        O[0] = q[0] + (aA00 + aB00) * inv0;
        O[1] = q[1] + (aA01 + aB01) * inv0;
        O[2] = q[2] + (aA02 + aB02) * inv0;
        O[3] = q[3] + (aA10 + aB10) * inv1;
        O[4] = q[4] + (aA11 + aB11) * inv1;
        O[5] = q[5] + (aA12 + aB12) * inv1;
    }

    {
        float mean = (O[0] + O[1] + O[2] + O[3] + O[4] + O[5]) * (1.f / 6.f);
        float var = 0.f;
#pragma unroll
        for (int j = 0; j < 6; ++j) { float d = O[j] - mean; var += d * d; }
        var *= (1.f / 6.f);
        float r = rsqrtf(var + 1e-5f);
#pragma unroll
        for (int j = 0; j < 6; ++j) O[j] = (O[j] - mean) * r * g0[j] + be0[j];
    }

    float f[6];
#pragma unroll
    for (int j = 0; j < 6; ++j) f[j] = O[j] + bf2[j];
#pragma unroll 4
    for (int r = 0; r < 24; ++r) {
        float hr = bf1[r];
#pragma unroll
        for (int j = 0; j < 6; ++j) hr += O[j] * Wf1[j * 24 + r];
        hr = fmaxf(hr, 0.f);
#pragma unroll
        for (int j = 0; j < 6; ++j) f[j] += hr * Wf2[r * 6 + j];
    }
    {
        float mean = (f[0] + f[1] + f[2] + f[3] + f[4] + f[5]) * (1.f / 6.f);
        float var = 0.f;
#pragma unroll
        for (int j = 0; j < 6; ++j) { float d = f[j] - mean; var += d * d; }
        var *= (1.f / 6.f);
        float r = rsqrtf(var + 1e-5f);
#pragma unroll
        for (int j = 0; j < 6; ++j) f[j] = (f[j] - mean) * r * g1[j] + be1[j];
    }

    float wr = Wrep[s];
#pragma unroll
    for (int j = 0; j < 6; ++j) {
        float val = f[j] * wr;
#pragma unroll
        for (int off = 16; off >= 1; off >>= 1) val += __shfl_xor(val, off, 32);
        f[j] = val;
    }
    if (s == 0) {
        float br = brep[0];
#pragma unroll
        for (int j = 0; j < 6; ++j) xt[(size_t)v * 6 + j] = f[j] + br;
    }
}

// ---------------------------------------------------------------------------
// xw1 = x @ W1 -> bf16 table (N,64); ai1 fp32 (N,8); aj1 packed bf16 (N,4 u32).
// ---------------------------------------------------------------------------
__global__ void __launch_bounds__(256) xw1_kernel(
    const float* __restrict__ x, const float* __restrict__ W1,
    const float* __restrict__ att1,
    __hip_bfloat16* __restrict__ xwb,
    float* __restrict__ ai, unsigned* __restrict__ ajp, int n)
{
    __shared__ float shW[4096];
    __shared__ float shX[256];
    int t = threadIdx.x, wv = t >> 6, l = t & 63;
#pragma unroll
    for (int i = 0; i < 16; ++i) shW[i * 256 + t] = W1[i * 256 + t];
    int h = l >> 3, c = l & 7;
    float a_i = att1[h * 16 + c];
    float a_j = att1[h * 16 + 8 + c];
    __syncthreads();

#pragma unroll
    for (int it = 0; it < 4; ++it) {
        int v = blockIdx.x * 16 + it * 4 + wv;
        shX[wv * 64 + l] = x[(size_t)v * 64 + l];
        __builtin_amdgcn_wave_barrier();
        float acc = 0.f;
#pragma unroll
        for (int k4 = 0; k4 < 16; ++k4) {
            float4 xb4 = *(const float4*)&shX[wv * 64 + k4 * 4];
            acc += xb4.x * shW[(k4 * 4 + 0) * 64 + l];
            acc += xb4.y * shW[(k4 * 4 + 1) * 64 + l];
            acc += xb4.z * shW[(k4 * 4 + 2) * 64 + l];
            acc += xb4.w * shW[(k4 * 4 + 3) * 64 + l];
        }
        xwb[(size_t)v * 64 + l] = __float2bfloat16(acc);

        float pi = acc * a_i;
        float pj = acc * a_j;
#pragma unroll
        for (int off = 1; off < 8; off <<= 1) {
            pi += __shfl_xor(pi, off, 64);
            pj += __shfl_xor(pj, off, 64);
        }
        if (c == 0) ai[(size_t)v * 8 + h] = pi;
        float pj_hi = __shfl(pj, (l + 8) & 63, 64);
        if ((l & 15) == 0)
            ajp[(size_t)v * 4 + (h >> 1)] = pk(pj, pj_hi);
        __builtin_amdgcn_wave_barrier();
    }
}

// ---------------------------------------------------------------------------
// CSR build: count -> 3-kernel scan -> scatter
// ---------------------------------------------------------------------------
__global__ void count_kernel(const int* __restrict__ src, const int* __restrict__ dst,
                             int* __restrict__ deg, int e)
{
    int i = blockIdx.x * blockDim.x + threadIdx.x;
    if (i < e) {
        int s = src[i], d = dst[i];
        if (s != d) atomicAdd(&deg[d], 1);
    }
}

__global__ void __launch_bounds__(1024) scan1_kernel(
    const int* __restrict__ deg, int* __restrict__ bsum, int n)
{
    __shared__ int sh[1024];
    int t = threadIdx.x;
    int i = blockIdx.x * 1024 + t;
    sh[t] = (i < n) ? deg[i] : 0;
    __syncthreads();
    for (int off = 512; off >= 1; off >>= 1) {
        if (t < off) sh[t] += sh[t + off];
        __syncthreads();
    }
    if (t == 0) bsum[blockIdx.x] = sh[0];
}

__global__ void __launch_bounds__(128) scan2_kernel(int* __restrict__ bsum, int nb)
{
    __shared__ int sh[128];
    int t = threadIdx.x;
    int v = (t < nb) ? bsum[t] : 0;
    sh[t] = v;
    __syncthreads();
    for (int off = 1; off < 128; off <<= 1) {
        int val = (t >= off) ? sh[t - off] : 0;
        __syncthreads();
        sh[t] += val;
        __syncthreads();
    }
    if (t < nb) bsum[t] = sh[t] - v;   // exclusive
}

__global__ void __launch_bounds__(1024) scan3_kernel(
    const int* __restrict__ deg, const int* __restrict__ bsum,
    int* __restrict__ offs, int n)
{
    __shared__ int sh[1024];
    int t = threadIdx.x;
    int i = blockIdx.x * 1024 + t;
    int v = (i < n) ? deg[i] : 0;
    sh[t] = v;
    __syncthreads();
    for (int off = 1; off < 1024; off <<= 1) {
        int val = (t >= off) ? sh[t - off] : 0;
        __syncthreads();
        sh[t] += val;
        __syncthreads();
    }
    if (i < n) offs[i] = bsum[blockIdx.x] + sh[t] - v;
}

__global__ void scatter_kernel(const int* __restrict__ src, const int* __restrict__ dst,
                               const int* __restrict__ offsets, int* __restrict__ cursor,
                               int* __restrict__ elist, int e)
{
    int i = blockIdx.x * blockDim.x + threadIdx.x;
    if (i < e) {
        int s = src[i], d = dst[i];
        if (s != d) {
            int pos = offsets[d] + atomicAdd(&cursor[d], 1);
            elist[pos] = s;
        }
    }
}

// ---------------------------------------------------------------------------
// GAT-1 aggregation, 8-edge chunks, two-phase (unchanged from R12).
// ---------------------------------------------------------------------------
__global__ void __launch_bounds__(256) agg1_kernel(
    const __hip_bfloat16* __restrict__ xwb, const float* __restrict__ ai1,
    const unsigned* __restrict__ ajp, const float* __restrict__ att1,
    const float* __restrict__ b1,
    const int* __restrict__ offs, const int* __restrict__ deg,
    const int* __restrict__ elist,
    __hip_bfloat16* __restrict__ h1b, int n)
{
    int t = threadIdx.x, wv = t >> 6, l = t & 63;
    int v = blockIdx.x * 4 + wv;
    int h = l >> 3, c = l & 7;    // output layout: lane = col l, head h
    int e1 = l >> 3, hp = l & 7;  // phase-1 layout: (edge slot e1, head hp)

    float ai_l = ai1[(size_t)v * 8 + h];
    float ai_p = ai1[(size_t)v * 8 + hp];
    float attj_l = att1[h * 16 + 8 + c];

    // self loop (output layout; butterfly over own row)
    float yself = __bfloat162float(xwb[(size_t)v * 64 + l]);
    float ps = yself * attj_l;
    ps += __shfl_xor(ps, 1, 64);
    ps += __shfl_xor(ps, 2, 64);
    ps += __shfl_xor(ps, 4, 64);
    float a = ai_l + ps;
    a = fmaxf(a, NEG_SLOPE * a);
    float ea  = __expf(a);
    float acc = ea * yself;

    float den_acc = 0.f;   // phase-1 layout
    int off = offs[v], dg = deg[v];
    for (int j = 0; j < dg; j += 8) {
        int idxv = 0;
        if (l < 8 && j + l < dg) idxv = elist[off + j + l];
        // phase 1: weights for 8 edges x 8 heads
        int se = __shfl(idxv, e1, 64);
        unsigned aw = ajp[(size_t)se * 4 + (hp >> 1)];
        float ajv = (hp & 1) ? bf_hi(aw) : bf_lo(aw);
        float u = ai_p + ajv;
        u = fmaxf(u, NEG_SLOPE * u);
        float wl = __expf(u);
        wl = (j + e1 < dg) ? wl : 0.f;
        den_acc += wl;
        // phase 2: gather + apply
#pragma unroll
        for (int b = 0; b < 8; ++b) {
            int s = __shfl(idxv, b, 64);
            float y = __bfloat162float(xwb[(size_t)s * 64 + l]);
            float w = __shfl(wl, b * 8 + h, 64);
            acc += w * y;
        }
    }
    den_acc += __shfl_xor(den_acc, 8, 64);
    den_acc += __shfl_xor(den_acc, 16, 64);
    den_acc += __shfl_xor(den_acc, 32, 64);
    float den = ea + __shfl(den_acc, h, 64);

    float o = acc / den + b1[l];
    o = o > 0.f ? o : expm1f(o);   // elu
    h1b[(size_t)v * 64 + l] = __float2bfloat16(o);
}

// ---------------------------------------------------------------------------
// xw2pack: packed xw2 rows [80 bf16 | 8 bf16 aj2 | pad] stride 128 u16, + ai2.
// R13: shH/shW2 padded to 72 rows; inner loop = 18 float4 LDS reads with
// 4 independent accumulator chains.
// ---------------------------------------------------------------------------
__global__ void __launch_bounds__(256) xw2pack_kernel(
    const __hip_bfloat16* __restrict__ h1b, const float* __restrict__ xt,
    const float* __restrict__ W2, const float* __restrict__ att2,
    __hip_bfloat16* __restrict__ xw2p, float* __restrict__ ai2, int n)
{
    __shared__ float shW2[5760];            // 72 rows x 80 (rows 70,71 = 0)
    __shared__ __align__(16) float shH[4][72];
    __shared__ float shR[4][80];
    int t = threadIdx.x, wv = t >> 6, l = t & 63;
    for (int i = t; i < 5760; i += 256) shW2[i] = (i < 5600) ? W2[i] : 0.f;
    __syncthreads();

#pragma unroll
    for (int it = 0; it < 4; ++it) {
        int v = blockIdx.x * 16 + it * 4 + wv;

        shH[wv][l] = __bfloat162float(h1b[(size_t)v * 64 + l]);
        if (l < 8) shH[wv][64 + l] = (l < 6) ? xt[(size_t)v * 6 + l] : 0.f;
        __builtin_amdgcn_wave_barrier();

        float a0 = 0.f, a0b = 0.f, a0c = 0.f, a0d = 0.f;
        float a1 = 0.f, a1b = 0.f, a1c = 0.f, a1d = 0.f;
        const float4* H4 = (const float4*)&shH[wv][0];
#pragma unroll
        for (int k4 = 0; k4 < 18; ++k4) {
            float4 hh = H4[k4];
            a0  += hh.x * shW2[(k4 * 4 + 0) * 80 + l];
            a0b += hh.y * shW2[(k4 * 4 + 1) * 80 + l];
            a0c += hh.z * shW2[(k4 * 4 + 2) * 80 + l];
            a0d += hh.w * shW2[(k4 * 4 + 3) * 80 + l];
            if (l < 16) {
                a1  += hh.x * shW2[(k4 * 4 + 0) * 80 + 64 + l];
                a1b += hh.y * shW2[(k4 * 4 + 1) * 80 + 64 + l];
                a1c += hh.z * shW2[(k4 * 4 + 2) * 80 + 64 + l];
                a1d += hh.w * shW2[(k4 * 4 + 3) * 80 + 64 + l];
            }
        }
        float r0 = (a0 + a0b) + (a0c + a0d);
        float r1 = (a1 + a1b) + (a1c + a1d);

        __hip_bfloat16* row = xw2p + (size_t)v * 128;
        row[l] = __float2bfloat16(r0);
        shR[wv][l] = r0;
        if (l < 16) {
            row[64 + l] = __float2bfloat16(r1);
            shR[wv][64 + l] = r1;
        }
        __builtin_amdgcn_wave_barrier();

        if (l < 16) {
            int hh = l >> 1, wj = l & 1;
            float sdot = 0.f;
#pragma unroll
            for (int cc = 0; cc < 10; ++cc)
                sdot += shR[wv][hh * 10 + cc] * att2[hh * 20 + wj * 10 + cc];
            if (wj == 0) ai2[(size_t)v * 8 + hh] = sdot;
            else         row[80 + hh] = __float2bfloat16(sdot);  // aj2 packed
        }
        __builtin_amdgcn_wave_barrier();
    }
}

// ---------------------------------------------------------------------------
// GAT-2 aggregation on packed rows, 8-edge chunks, two-phase (unchanged).
// ---------------------------------------------------------------------------
__global__ void __launch_bounds__(256) agg2_kernel(
    const unsigned* __restrict__ xw2p, const float* __restrict__ ai2,
    const float* __restrict__ b2,
    const int* __restrict__ offs, const int* __restrict__ deg,
    const int* __restrict__ elist, float* __restrict__ out, int n)
{
    __shared__ float buf[4][80];
    __shared__ float buf2[4][10];
    int t = threadIdx.x, wv = t >> 6, l = t & 63;
    int v = blockIdx.x * 4 + wv;

    int hc = (l < 40) ? (l / 5) : 0;
    int e1 = l >> 3, hp = l & 7;
    float ai_p = ai2[(size_t)v * 8 + hp];
    float ai_l = (l < 40) ? ai2[(size_t)v * 8 + hc] : 0.f;

    // self loop
    bool act = l < 44;
    unsigned selfw = act ? xw2p[(size_t)v * 64 + l] : 0u;
    int ajl = 40 + (hc >> 1);
    unsigned ajw = __shfl(selfw, ajl, 64);
    float ajs = (hc & 1) ? bf_hi(ajw) : bf_lo(ajw);
    float a = ai_l + ajs;
    a = fmaxf(a, NEG_SLOPE * a);
    float e0 = __expf(a);
    float acc0 = e0 * bf_lo(selfw), acc1 = e0 * bf_hi(selfw);

    float den_acc = 0.f;   // phase-1 layout
    int off = offs[v], dg = deg[v];
    for (int j = 0; j < dg; j += 8) {
        int idxv = 0;
        if (l < 8 && j + l < dg) idxv = elist[off + j + l];
        // phase 1: weights for 8 edges x 8 heads (aj words in-row at 40+h/2)
        int se = __shfl(idxv, e1, 64);
        unsigned aw = xw2p[(size_t)se * 64 + 40 + (hp >> 1)];
        float ajv = (hp & 1) ? bf_hi(aw) : bf_lo(aw);
        float u = ai_p + ajv;
        u = fmaxf(u, NEG_SLOPE * u);
        float wl = __expf(u);
        wl = (j + e1 < dg) ? wl : 0.f;
        den_acc += wl;
        // phase 2
#pragma unroll
        for (int b = 0; b < 8; ++b) {
            int s = __shfl(idxv, b, 64);
            unsigned yw = (l < 40) ? xw2p[(size_t)s * 64 + l] : 0u;
            float w = __shfl(wl, b * 8 + hc, 64);
            acc0 += w * bf_lo(yw);
            acc1 += w * bf_hi(yw);
        }
    }
    den_acc += __shfl_xor(den_acc, 8, 64);
    den_acc += __shfl_xor(den_acc, 16, 64);
    den_acc += __shfl_xor(den_acc, 32, 64);
    float den = e0 + __shfl(den_acc, hc, 64);

    if (l < 40) {
        float inv = 1.f / den;
        buf[wv][2 * l]     = acc0 * inv;
        buf[wv][2 * l + 1] = acc1 * inv;
    }
    __builtin_amdgcn_wave_barrier();
    if (l < 10) {
        float mval = 0.f;
#pragma unroll
        for (int hh = 0; hh < 8; ++hh) mval += buf[wv][hh * 10 + l];
        buf2[wv][l] = mval * 0.125f + b2[l];
    }
    __builtin_amdgcn_wave_barrier();
    if (l < 10) {
        float mx = -1e30f;
#pragma unroll
        for (int cc = 0; cc < 10; ++cc) mx = fmaxf(mx, buf2[wv][cc]);
        float se = 0.f;
#pragma unroll
        for (int cc = 0; cc < 10; ++cc) se += __expf(buf2[wv][cc] - mx);
        out[(size_t)v * 10 + l] = buf2[wv][l] - mx - __logf(se);
    }
}

// ---------------------------------------------------------------------------
extern "C" void kernel_launch(void* const* d_in, const int* in_sizes, int n_in,
                              void* d_out, int out_size, void* d_ws, size_t ws_size,
                              hipStream_t stream)
{
    const float* x    = (const float*)d_in[0];
    const int*   ei   = (const int*)  d_in[1];
    const float* ef   = (const float*)d_in[2];
    const float* W1   = (const float*)d_in[3];
    const float* att1 = (const float*)d_in[4];
    const float* b1   = (const float*)d_in[5];
    const float* W2   = (const float*)d_in[6];
    const float* att2 = (const float*)d_in[7];
    const float* b2   = (const float*)d_in[8];
    const float* Wq   = (const float*)d_in[9];
    const float* bq   = (const float*)d_in[10];
    const float* Wk   = (const float*)d_in[11];
    const float* bk   = (const float*)d_in[12];
    const float* Wv   = (const float*)d_in[13];
    const float* bv   = (const float*)d_in[14];
    const float* g0   = (const float*)d_in[15];
    const float* be0  = (const float*)d_in[16];
    const float* Wf1  = (const float*)d_in[17];
    const float* bf1  = (const float*)d_in[18];
    const float* Wf2  = (const float*)d_in[19];
    const float* bf2  = (const float*)d_in[20];
    const float* g1   = (const float*)d_in[21];
    const float* be1  = (const float*)d_in[22];
    const float* Wrep = (const float*)d_in[23];
    const float* brep = (const float*)d_in[24];

    const int n = in_sizes[0] / 64;   // 100000
    const int e = in_sizes[1] / 2;    // 1600000
    const int* src = ei;
    const int* dst = ei + e;

    char* ws = (char*)d_ws;
    size_t o = 0;
    auto alloc = [&](size_t bytes) -> void* {
        void* p = ws + o;
        o += (bytes + 255) & ~(size_t)255;
        return p;
    };
    __hip_bfloat16* xw1b = (__hip_bfloat16*)alloc((size_t)n * 64 * 2);
    __hip_bfloat16* h1b  = (__hip_bfloat16*)alloc((size_t)n * 64 * 2);
    __hip_bfloat16* xw2p = (__hip_bfloat16*)alloc((size_t)n * 128 * 2); // packed
    unsigned* ajp = (unsigned*)alloc((size_t)n * 4 * 4);  // packed bf16 aj1
    float* ai1   = (float*)alloc((size_t)n * 8 * 4);
    float* ai2   = (float*)alloc((size_t)n * 8 * 4);
    float* xt    = (float*)alloc((size_t)n * 6 * 4);
    int*   deg   = (int*)  alloc((size_t)n * 4);
    int*   offs  = (int*)  alloc((size_t)n * 4);
    int*   cur   = (int*)  alloc((size_t)n * 4);
    int*   bsum  = (int*)  alloc(256 * 4);
    int*   elist = (int*)  alloc((size_t)e * 4);
    (void)ws_size; (void)n_in; (void)out_size;

    hipMemsetAsync(deg, 0, (size_t)n * 4, stream);
    hipMemsetAsync(cur, 0, (size_t)n * 4, stream);

    const int NB = (n + 1023) / 1024;    // 98 scan blocks

    count_kernel<<<(e + 255) / 256, 256, 0, stream>>>(src, dst, deg, e);
    encoder_kernel<<<n / 8, 256, 0, stream>>>(ef, Wq, bq, Wk, bk, Wv, bv, g0, be0,
                                              Wf1, bf1, Wf2, bf2, g1, be1, Wrep, brep,
                                              xt, n);
    xw1_kernel<<<n / 16, 256, 0, stream>>>(x, W1, att1, xw1b, ai1, ajp, n);
    scan1_kernel<<<NB, 1024, 0, stream>>>(deg, bsum, n);
    scan2_kernel<<<1, 128, 0, stream>>>(bsum, NB);
    scan3_kernel<<<NB, 1024, 0, stream>>>(deg, bsum, offs, n);
    scatter_kernel<<<(e + 255) / 256, 256, 0, stream>>>(src, dst, offs, cur, elist, e);
    agg1_kernel<<<n / 4, 256, 0, stream>>>(xw1b, ai1, ajp, att1, b1,
                                           offs, deg, elist, h1b, n);
    xw2pack_kernel<<<n / 16, 256, 0, stream>>>(h1b, xt, W2, att2, xw2p, ai2, n);
    agg2_kernel<<<n / 4, 256, 0, stream>>>((const unsigned*)xw2p, ai2, b2,
                                           offs, deg, elist, (float*)d_out, n);
}

// Round 14
// 533.391 us; speedup vs baseline: 1.2863x; 1.2863x over previous
//
#include <hip/hip_runtime.h>
#include <hip/hip_bf16.h>

// N=100000, E=1600000.
// R14: xw2pack replaced by MFMA GEMM. hx[N][96] bf16 = [h1(64) | xt(6) | 0pad];
// W2extT[96][96] bf16 = [W2 | W2@Ai | W2@Aj]^T. One 16x16x32-bf16 MFMA GEMM
// emits packed xw2 rows + ai2 + aj2. agg kernels unchanged from R12.

#define NEG_SLOPE 0.2f

using short8  = __attribute__((ext_vector_type(8))) short;
using floatx4 = __attribute__((ext_vector_type(4))) float;

__device__ __forceinline__ float bf_lo(unsigned u) { return __uint_as_float(u << 16); }
__device__ __forceinline__ float bf_hi(unsigned u) { return __uint_as_float(u & 0xffff0000u); }
__device__ __forceinline__ unsigned pk(float lo, float hi)
{
    __hip_bfloat16 l = __float2bfloat16(lo), h = __float2bfloat16(hi);
    unsigned ul = reinterpret_cast<unsigned short&>(l);
    unsigned uh = reinterpret_cast<unsigned short&>(h);
    return ul | (uh << 16);
}

// ---------------------------------------------------------------------------
// Encoder: 8 nodes/block, 32 lanes/node. K/V staged as bf16 (32B/token).
// Writes xt (bf16) into hx cols 64..69.
// ---------------------------------------------------------------------------
__global__ void __launch_bounds__(256) encoder_kernel(
    const float* __restrict__ Xf,
    const float* __restrict__ Wq, const float* __restrict__ bq,
    const float* __restrict__ Wk, const float* __restrict__ bk,
    const float* __restrict__ Wv, const float* __restrict__ bv,
    const float* __restrict__ g0, const float* __restrict__ be0,
    const float* __restrict__ Wf1, const float* __restrict__ bf1,
    const float* __restrict__ Wf2, const float* __restrict__ bf2,
    const float* __restrict__ g1, const float* __restrict__ be1,
    const float* __restrict__ Wrep, const float* __restrict__ brep,
    __hip_bfloat16* __restrict__ hx, int n)
{
    __shared__ float sh[2560];
    int t = threadIdx.x;
    int bid = blockIdx.x;
    size_t base = (size_t)bid * 2560;
#pragma unroll
    for (int i = 0; i < 10; ++i) sh[i * 256 + t] = Xf[base + i * 256 + t];
    __syncthreads();

    int sub = t >> 5;
    int s   = t & 31;
    int v   = bid * 8 + sub;

    float xv[10];
#pragma unroll
    for (int i = 0; i < 10; ++i) xv[i] = sh[sub * 320 + s * 10 + i];
    __syncthreads();   // Xf consumed; slab reused for bf16 K/V

    float q[6], k[6], w[6];
#pragma unroll
    for (int j = 0; j < 6; ++j) { q[j] = bq[j]; k[j] = bk[j]; w[j] = bv[j]; }
#pragma unroll
    for (int i = 0; i < 10; ++i) {
#pragma unroll
        for (int j = 0; j < 6; ++j) {
            q[j] += xv[i] * Wq[i * 6 + j];
            k[j] += xv[i] * Wk[i * 6 + j];
            w[j] += xv[i] * Wv[i * 6 + j];
        }
    }

    uint4* shu = (uint4*)sh;
    int nb = sub * 64;
    shu[nb + s * 2]     = make_uint4(pk(k[0], k[1]), pk(k[2], k[3]),
                                     pk(k[4], k[5]), pk(w[0], w[1]));
    shu[nb + s * 2 + 1] = make_uint4(pk(w[2], w[3]), pk(w[4], w[5]), 0u, 0u);
    __builtin_amdgcn_wave_barrier();

    const float scale = 0.40824829046386301637f;  // 1/sqrt(6)
    float q0s = q[0] * scale, q1s = q[1] * scale, q2s = q[2] * scale;
    float q3s = q[3] * scale, q4s = q[4] * scale, q5s = q[5] * scale;

    float dA0 = 0.f, dB0 = 0.f, dA1 = 0.f, dB1 = 0.f;
    float aA00 = 0.f, aA01 = 0.f, aA02 = 0.f;
    float aB00 = 0.f, aB01 = 0.f, aB02 = 0.f;
    float aA10 = 0.f, aA11 = 0.f, aA12 = 0.f;
    float aB10 = 0.f, aB11 = 0.f, aB12 = 0.f;

#pragma unroll 4
    for (int t2 = 0; t2 < 32; t2 += 2) {
        uint4 Ua = shu[nb + t2 * 2];
        uint4 Ub = shu[nb + t2 * 2 + 1];
        uint4 Uc = shu[nb + t2 * 2 + 2];
        uint4 Ud = shu[nb + t2 * 2 + 3];
        {
            float k0 = bf_lo(Ua.x), k1 = bf_hi(Ua.x);
            float k2 = bf_lo(Ua.y), k3 = bf_hi(Ua.y);
            float k4 = bf_lo(Ua.z), k5 = bf_hi(Ua.z);
            float v0 = bf_lo(Ua.w), v1 = bf_hi(Ua.w);
            float v2 = bf_lo(Ub.x), v3 = bf_hi(Ub.x);
            float v4 = bf_lo(Ub.y), v5 = bf_hi(Ub.y);
            float p0 = __expf(q0s * k0 + q1s * k1 + q2s * k2);
            float p1 = __expf(q3s * k3 + q4s * k4 + q5s * k5);
            dA0 += p0; aA00 += p0 * v0; aA01 += p0 * v1; aA02 += p0 * v2;
            dA1 += p1; aA10 += p1 * v3; aA11 += p1 * v4; aA12 += p1 * v5;
        }
        {
            float k0 = bf_lo(Uc.x), k1 = bf_hi(Uc.x);
            float k2 = bf_lo(Uc.y), k3 = bf_hi(Uc.y);
            float k4 = bf_lo(Uc.z), k5 = bf_hi(Uc.z);
            float v0 = bf_lo(Uc.w), v1 = bf_hi(Uc.w);
            float v2 = bf_lo(Ud.x), v3 = bf_hi(Ud.x);
            float v4 = bf_lo(Ud.y), v5 = bf_hi(Ud.y);
            float p0 = __expf(q0s * k0 + q1s * k1 + q2s * k2);
            float p1 = __expf(q3s * k3 + q4s * k4 + q5s * k5);
            dB0 += p0; aB00 += p0 * v0; aB01 += p0 * v1; aB02 += p0 * v2;
            dB1 += p1; aB10 += p1 * v3; aB11 += p1 * v4; aB12 += p1 * v5;
        }
    }

    float O[6];
    {
        float inv0 = 1.f / (dA0 + dB0);
        float inv1 = 1.f / (dA1 + dB1);
        O[0] = q[0] + (aA00 + aB00) * inv0;
        O[1] = q[1] + (aA01 + aB01) * inv0;
        O[2] = q[2] + (aA02 + aB02) * inv0;
        O[3] = q[3] + (aA10 + aB10) * inv1;
        O[4] = q[4] + (aA11 + aB11) * inv1;
        O[5] = q[5] + (aA12 + aB12) * inv1;
    }

    {
        float mean = (O[0] + O[1] + O[2] + O[3] + O[4] + O[5]) * (1.f / 6.f);
        float var = 0.f;
#pragma unroll
        for (int j = 0; j < 6; ++j) { float d = O[j] - mean; var += d * d; }
        var *= (1.f / 6.f);
        float r = rsqrtf(var + 1e-5f);
#pragma unroll
        for (int j = 0; j < 6; ++j) O[j] = (O[j] - mean) * r * g0[j] + be0[j];
    }

    float f[6];
#pragma unroll
    for (int j = 0; j < 6; ++j) f[j] = O[j] + bf2[j];
#pragma unroll 4
    for (int r = 0; r < 24; ++r) {
        float hr = bf1[r];
#pragma unroll
        for (int j = 0; j < 6; ++j) hr += O[j] * Wf1[j * 24 + r];
        hr = fmaxf(hr, 0.f);
#pragma unroll
        for (int j = 0; j < 6; ++j) f[j] += hr * Wf2[r * 6 + j];
    }
    {
        float mean = (f[0] + f[1] + f[2] + f[3] + f[4] + f[5]) * (1.f / 6.f);
        float var = 0.f;
#pragma unroll
        for (int j = 0; j < 6; ++j) { float d = f[j] - mean; var += d * d; }
        var *= (1.f / 6.f);
        float r = rsqrtf(var + 1e-5f);
#pragma unroll
        for (int j = 0; j < 6; ++j) f[j] = (f[j] - mean) * r * g1[j] + be1[j];
    }

    float wr = Wrep[s];
#pragma unroll
    for (int j = 0; j < 6; ++j) {
        float val = f[j] * wr;
#pragma unroll
        for (int off = 16; off >= 1; off >>= 1) val += __shfl_xor(val, off, 32);
        f[j] = val;
    }
    if (s == 0) {
        float br = brep[0];
#pragma unroll
        for (int j = 0; j < 6; ++j)
            hx[(size_t)v * 96 + 64 + j] = __float2bfloat16(f[j] + br);
    }
}

// ---------------------------------------------------------------------------
// xw1 = x @ W1 -> bf16 table (N,64); ai1 fp32 (N,8); aj1 packed bf16 (N,4 u32).
// ---------------------------------------------------------------------------
__global__ void __launch_bounds__(256) xw1_kernel(
    const float* __restrict__ x, const float* __restrict__ W1,
    const float* __restrict__ att1,
    __hip_bfloat16* __restrict__ xwb,
    float* __restrict__ ai, unsigned* __restrict__ ajp, int n)
{
    __shared__ float shW[4096];
    __shared__ float shX[256];
    int t = threadIdx.x, wv = t >> 6, l = t & 63;
#pragma unroll
    for (int i = 0; i < 16; ++i) shW[i * 256 + t] = W1[i * 256 + t];
    int h = l >> 3, c = l & 7;
    float a_i = att1[h * 16 + c];
    float a_j = att1[h * 16 + 8 + c];
    __syncthreads();

#pragma unroll
    for (int it = 0; it < 4; ++it) {
        int v = blockIdx.x * 16 + it * 4 + wv;
        shX[wv * 64 + l] = x[(size_t)v * 64 + l];
        __builtin_amdgcn_wave_barrier();
        float acc = 0.f;
#pragma unroll
        for (int k4 = 0; k4 < 16; ++k4) {
            float4 xb4 = *(const float4*)&shX[wv * 64 + k4 * 4];
            acc += xb4.x * shW[(k4 * 4 + 0) * 64 + l];
            acc += xb4.y * shW[(k4 * 4 + 1) * 64 + l];
            acc += xb4.z * shW[(k4 * 4 + 2) * 64 + l];
            acc += xb4.w * shW[(k4 * 4 + 3) * 64 + l];
        }
        xwb[(size_t)v * 64 + l] = __float2bfloat16(acc);

        float pi = acc * a_i;
        float pj = acc * a_j;
#pragma unroll
        for (int off = 1; off < 8; off <<= 1) {
            pi += __shfl_xor(pi, off, 64);
            pj += __shfl_xor(pj, off, 64);
        }
        if (c == 0) ai[(size_t)v * 8 + h] = pi;
        float pj_hi = __shfl(pj, (l + 8) & 63, 64);
        if ((l & 15) == 0)
            ajp[(size_t)v * 4 + (h >> 1)] = pk(pj, pj_hi);
        __builtin_amdgcn_wave_barrier();
    }
}

// ---------------------------------------------------------------------------
// CSR build: count -> 3-kernel scan -> scatter
// ---------------------------------------------------------------------------
__global__ void count_kernel(const int* __restrict__ src, const int* __restrict__ dst,
                             int* __restrict__ deg, int e)
{
    int i = blockIdx.x * blockDim.x + threadIdx.x;
    if (i < e) {
        int s = src[i], d = dst[i];
        if (s != d) atomicAdd(&deg[d], 1);
    }
}

__global__ void __launch_bounds__(1024) scan1_kernel(
    const int* __restrict__ deg, int* __restrict__ bsum, int n)
{
    __shared__ int sh[1024];
    int t = threadIdx.x;
    int i = blockIdx.x * 1024 + t;
    sh[t] = (i < n) ? deg[i] : 0;
    __syncthreads();
    for (int off = 512; off >= 1; off >>= 1) {
        if (t < off) sh[t] += sh[t + off];
        __syncthreads();
    }
    if (t == 0) bsum[blockIdx.x] = sh[0];
}

__global__ void __launch_bounds__(128) scan2_kernel(int* __restrict__ bsum, int nb)
{
    __shared__ int sh[128];
    int t = threadIdx.x;
    int v = (t < nb) ? bsum[t] : 0;
    sh[t] = v;
    __syncthreads();
    for (int off = 1; off < 128; off <<= 1) {
        int val = (t >= off) ? sh[t - off] : 0;
        __syncthreads();
        sh[t] += val;
        __syncthreads();
    }
    if (t < nb) bsum[t] = sh[t] - v;   // exclusive
}

__global__ void __launch_bounds__(1024) scan3_kernel(
    const int* __restrict__ deg, const int* __restrict__ bsum,
    int* __restrict__ offs, int n)
{
    __shared__ int sh[1024];
    int t = threadIdx.x;
    int i = blockIdx.x * 1024 + t;
    int v = (i < n) ? deg[i] : 0;
    sh[t] = v;
    __syncthreads();
    for (int off = 1; off < 1024; off <<= 1) {
        int val = (t >= off) ? sh[t - off] : 0;
        __syncthreads();
        sh[t] += val;
        __syncthreads();
    }
    if (i < n) offs[i] = bsum[blockIdx.x] + sh[t] - v;
}

__global__ void scatter_kernel(const int* __restrict__ src, const int* __restrict__ dst,
                               const int* __restrict__ offsets, int* __restrict__ cursor,
                               int* __restrict__ elist, int e)
{
    int i = blockIdx.x * blockDim.x + threadIdx.x;
    if (i < e) {
        int s = src[i], d = dst[i];
        if (s != d) {
            int pos = offsets[d] + atomicAdd(&cursor[d], 1);
            elist[pos] = s;
        }
    }
}

// ---------------------------------------------------------------------------
// GAT-1 aggregation, 8-edge chunks, two-phase (R12 structure).
// Output h1 (bf16) into hx rows (stride 96), cols 0..63.
// ---------------------------------------------------------------------------
__global__ void __launch_bounds__(256) agg1_kernel(
    const __hip_bfloat16* __restrict__ xwb, const float* __restrict__ ai1,
    const unsigned* __restrict__ ajp, const float* __restrict__ att1,
    const float* __restrict__ b1,
    const int* __restrict__ offs, const int* __restrict__ deg,
    const int* __restrict__ elist,
    __hip_bfloat16* __restrict__ hx, int n)
{
    int t = threadIdx.x, wv = t >> 6, l = t & 63;
    int v = blockIdx.x * 4 + wv;
    int h = l >> 3, c = l & 7;    // output layout: lane = col l, head h
    int e1 = l >> 3, hp = l & 7;  // phase-1 layout: (edge slot e1, head hp)

    float ai_l = ai1[(size_t)v * 8 + h];
    float ai_p = ai1[(size_t)v * 8 + hp];
    float attj_l = att1[h * 16 + 8 + c];

    // self loop (output layout; butterfly over own row)
    float yself = __bfloat162float(xwb[(size_t)v * 64 + l]);
    float ps = yself * attj_l;
    ps += __shfl_xor(ps, 1, 64);
    ps += __shfl_xor(ps, 2, 64);
    ps += __shfl_xor(ps, 4, 64);
    float a = ai_l + ps;
    a = fmaxf(a, NEG_SLOPE * a);
    float ea  = __expf(a);
    float acc = ea * yself;

    float den_acc = 0.f;   // phase-1 layout
    int off = offs[v], dg = deg[v];
    for (int j = 0; j < dg; j += 8) {
        int idxv = 0;
        if (l < 8 && j + l < dg) idxv = elist[off + j + l];
        // phase 1: weights for 8 edges x 8 heads
        int se = __shfl(idxv, e1, 64);
        unsigned aw = ajp[(size_t)se * 4 + (hp >> 1)];
        float ajv = (hp & 1) ? bf_hi(aw) : bf_lo(aw);
        float u = ai_p + ajv;
        u = fmaxf(u, NEG_SLOPE * u);
        float wl = __expf(u);
        wl = (j + e1 < dg) ? wl : 0.f;
        den_acc += wl;
        // phase 2: gather + apply
#pragma unroll
        for (int b = 0; b < 8; ++b) {
            int s = __shfl(idxv, b, 64);
            float y = __bfloat162float(xwb[(size_t)s * 64 + l]);
            float w = __shfl(wl, b * 8 + h, 64);
            acc += w * y;
        }
    }
    den_acc += __shfl_xor(den_acc, 8, 64);
    den_acc += __shfl_xor(den_acc, 16, 64);
    den_acc += __shfl_xor(den_acc, 32, 64);
    float den = ea + __shfl(den_acc, h, 64);

    float o = acc / den + b1[l];
    o = o > 0.f ? o : expm1f(o);   // elu
    hx[(size_t)v * 96 + l] = __float2bfloat16(o);
}

// ---------------------------------------------------------------------------
// W2extT build: w2t[j][k] (96x96 bf16), j = output col, k = input row.
// cols 0..79 = W2; 80..87 = W2 @ att2_i (per head); 88..95 = W2 @ att2_j.
// ---------------------------------------------------------------------------
__global__ void __launch_bounds__(256) w2ext_kernel(
    const float* __restrict__ W2, const float* __restrict__ att2,
    __hip_bfloat16* __restrict__ w2t)
{
    int idx = blockIdx.x * 256 + threadIdx.x;
    if (idx >= 96 * 96) return;
    int j = idx / 96, k = idx % 96;
    float val = 0.f;
    if (k < 70) {
        if (j < 80) {
            val = W2[k * 80 + j];
        } else if (j < 88) {
            int h = j - 80;
            for (int c = 0; c < 10; ++c)
                val += W2[k * 80 + h * 10 + c] * att2[h * 20 + c];
        } else {
            int h = j - 88;
            for (int c = 0; c < 10; ++c)
                val += W2[k * 80 + h * 10 + c] * att2[h * 20 + 10 + c];
        }
    }
    w2t[j * 96 + k] = __float2bfloat16(val);
}

// ---------------------------------------------------------------------------
// xw2 GEMM via MFMA: D[N x 96] = hx[N x 96] @ W2ext, 16 nodes per wave.
// A-frag: row=l&15, k=(l>>4)*8..+7 (16B load). B-frag from w2t (B^T layout).
// D: col=lane&15, row=(lane>>4)*4+reg. Epilogue scatters packed row + ai2.
// ---------------------------------------------------------------------------
__global__ void __launch_bounds__(256) xw2mfma_kernel(
    const __hip_bfloat16* __restrict__ hx, const __hip_bfloat16* __restrict__ w2t,
    __hip_bfloat16* __restrict__ xw2p, float* __restrict__ ai2, int n)
{
    int t = threadIdx.x, wv = t >> 6, l = t & 63;
    int base = blockIdx.x * 64 + wv * 16;
    if (base >= n) return;           // per-wave guard; no block barriers here

    int mrow = l & 15;               // A-row within tile / D-col
    int kc   = (l >> 4) * 8;         // k sub-offset (elements)
    int dr0  = (l >> 4) * 4;         // D-row base

    const short* hp = (const short*)hx;
    const short* wp = (const short*)w2t;

    short8 a0 = *(const short8*)(hp + (size_t)(base + mrow) * 96 + 0  + kc);
    short8 a1 = *(const short8*)(hp + (size_t)(base + mrow) * 96 + 32 + kc);
    short8 a2 = *(const short8*)(hp + (size_t)(base + mrow) * 96 + 64 + kc);

#pragma unroll
    for (int nt = 0; nt < 6; ++nt) {
        int col = nt * 16 + mrow;
        short8 b0 = *(const short8*)(wp + (size_t)col * 96 + 0  + kc);
        short8 b1 = *(const short8*)(wp + (size_t)col * 96 + 32 + kc);
        short8 b2 = *(const short8*)(wp + (size_t)col * 96 + 64 + kc);
        floatx4 acc = {0.f, 0.f, 0.f, 0.f};
        acc = __builtin_amdgcn_mfma_f32_16x16x32_bf16(a0, b0, acc, 0, 0, 0);
        acc = __builtin_amdgcn_mfma_f32_16x16x32_bf16(a1, b1, acc, 0, 0, 0);
        acc = __builtin_amdgcn_mfma_f32_16x16x32_bf16(a2, b2, acc, 0, 0, 0);
#pragma unroll
        for (int r = 0; r < 4; ++r) {
            int m = base + dr0 + r;
            float val = acc[r];
            if (nt < 5) {
                xw2p[(size_t)m * 128 + nt * 16 + mrow] = __float2bfloat16(val);
            } else {
                if (mrow < 8) ai2[(size_t)m * 8 + mrow] = val;
                else xw2p[(size_t)m * 128 + 80 + (mrow - 8)] = __float2bfloat16(val);
            }
        }
    }
}

// ---------------------------------------------------------------------------
// GAT-2 aggregation on packed rows, 8-edge chunks, two-phase (unchanged).
// ---------------------------------------------------------------------------
__global__ void __launch_bounds__(256) agg2_kernel(
    const unsigned* __restrict__ xw2p, const float* __restrict__ ai2,
    const float* __restrict__ b2,
    const int* __restrict__ offs, const int* __restrict__ deg,
    const int* __restrict__ elist, float* __restrict__ out, int n)
{
    __shared__ float buf[4][80];
    __shared__ float buf2[4][10];
    int t = threadIdx.x, wv = t >> 6, l = t & 63;
    int v = blockIdx.x * 4 + wv;

    int hc = (l < 40) ? (l / 5) : 0;
    int e1 = l >> 3, hp = l & 7;
    float ai_p = ai2[(size_t)v * 8 + hp];
    float ai_l = (l < 40) ? ai2[(size_t)v * 8 + hc] : 0.f;

    // self loop
    bool act = l < 44;
    unsigned selfw = act ? xw2p[(size_t)v * 64 + l] : 0u;
    int ajl = 40 + (hc >> 1);
    unsigned ajw = __shfl(selfw, ajl, 64);
    float ajs = (hc & 1) ? bf_hi(ajw) : bf_lo(ajw);
    float a = ai_l + ajs;
    a = fmaxf(a, NEG_SLOPE * a);
    float e0 = __expf(a);
    float acc0 = e0 * bf_lo(selfw), acc1 = e0 * bf_hi(selfw);

    float den_acc = 0.f;   // phase-1 layout
    int off = offs[v], dg = deg[v];
    for (int j = 0; j < dg; j += 8) {
        int idxv = 0;
        if (l < 8 && j + l < dg) idxv = elist[off + j + l];
        // phase 1: weights for 8 edges x 8 heads (aj words in-row at 40+h/2)
        int se = __shfl(idxv, e1, 64);
        unsigned aw = xw2p[(size_t)se * 64 + 40 + (hp >> 1)];
        float ajv = (hp & 1) ? bf_hi(aw) : bf_lo(aw);
        float u = ai_p + ajv;
        u = fmaxf(u, NEG_SLOPE * u);
        float wl = __expf(u);
        wl = (j + e1 < dg) ? wl : 0.f;
        den_acc += wl;
        // phase 2
#pragma unroll
        for (int b = 0; b < 8; ++b) {
            int s = __shfl(idxv, b, 64);
            unsigned yw = (l < 40) ? xw2p[(size_t)s * 64 + l] : 0u;
            float w = __shfl(wl, b * 8 + hc, 64);
            acc0 += w * bf_lo(yw);
            acc1 += w * bf_hi(yw);
        }
    }
    den_acc += __shfl_xor(den_acc, 8, 64);
    den_acc += __shfl_xor(den_acc, 16, 64);
    den_acc += __shfl_xor(den_acc, 32, 64);
    float den = e0 + __shfl(den_acc, hc, 64);

    if (l < 40) {
        float inv = 1.f / den;
        buf[wv][2 * l]     = acc0 * inv;
        buf[wv][2 * l + 1] = acc1 * inv;
    }
    __builtin_amdgcn_wave_barrier();
    if (l < 10) {
        float mval = 0.f;
#pragma unroll
        for (int hh = 0; hh < 8; ++hh) mval += buf[wv][hh * 10 + l];
        buf2[wv][l] = mval * 0.125f + b2[l];
    }
    __builtin_amdgcn_wave_barrier();
    if (l < 10) {
        float mx = -1e30f;
#pragma unroll
        for (int cc = 0; cc < 10; ++cc) mx = fmaxf(mx, buf2[wv][cc]);
        float se = 0.f;
#pragma unroll
        for (int cc = 0; cc < 10; ++cc) se += __expf(buf2[wv][cc] - mx);
        out[(size_t)v * 10 + l] = buf2[wv][l] - mx - __logf(se);
    }
}

// ---------------------------------------------------------------------------
extern "C" void kernel_launch(void* const* d_in, const int* in_sizes, int n_in,
                              void* d_out, int out_size, void* d_ws, size_t ws_size,
                              hipStream_t stream)
{
    const float* x    = (const float*)d_in[0];
    const int*   ei   = (const int*)  d_in[1];
    const float* ef   = (const float*)d_in[2];
    const float* W1   = (const float*)d_in[3];
    const float* att1 = (const float*)d_in[4];
    const float* b1   = (const float*)d_in[5];
    const float* W2   = (const float*)d_in[6];
    const float* att2 = (const float*)d_in[7];
    const float* b2   = (const float*)d_in[8];
    const float* Wq   = (const float*)d_in[9];
    const float* bq   = (const float*)d_in[10];
    const float* Wk   = (const float*)d_in[11];
    const float* bk   = (const float*)d_in[12];
    const float* Wv   = (const float*)d_in[13];
    const float* bv   = (const float*)d_in[14];
    const float* g0   = (const float*)d_in[15];
    const float* be0  = (const float*)d_in[16];
    const float* Wf1  = (const float*)d_in[17];
    const float* bf1  = (const float*)d_in[18];
    const float* Wf2  = (const float*)d_in[19];
    const float* bf2  = (const float*)d_in[20];
    const float* g1   = (const float*)d_in[21];
    const float* be1  = (const float*)d_in[22];
    const float* Wrep = (const float*)d_in[23];
    const float* brep = (const float*)d_in[24];

    const int n = in_sizes[0] / 64;   // 100000
    const int e = in_sizes[1] / 2;    // 1600000
    const int* src = ei;
    const int* dst = ei + e;

    char* ws = (char*)d_ws;
    size_t o = 0;
    auto alloc = [&](size_t bytes) -> void* {
        void* p = ws + o;
        o += (bytes + 255) & ~(size_t)255;
        return p;
    };
    __hip_bfloat16* xw1b = (__hip_bfloat16*)alloc((size_t)n * 64 * 2);
    __hip_bfloat16* hx   = (__hip_bfloat16*)alloc((size_t)n * 96 * 2);  // h1|xt|0
    __hip_bfloat16* xw2p = (__hip_bfloat16*)alloc((size_t)n * 128 * 2); // packed
    __hip_bfloat16* w2t  = (__hip_bfloat16*)alloc(96 * 96 * 2);
    unsigned* ajp = (unsigned*)alloc((size_t)n * 4 * 4);  // packed bf16 aj1
    float* ai1   = (float*)alloc((size_t)n * 8 * 4);
    float* ai2   = (float*)alloc((size_t)n * 8 * 4);
    int*   deg   = (int*)  alloc((size_t)n * 4);
    int*   offs  = (int*)  alloc((size_t)n * 4);
    int*   cur   = (int*)  alloc((size_t)n * 4);
    int*   bsum  = (int*)  alloc(256 * 4);
    int*   elist = (int*)  alloc((size_t)e * 4);
    (void)ws_size; (void)n_in; (void)out_size;

    hipMemsetAsync(deg, 0, (size_t)n * 4, stream);
    hipMemsetAsync(cur, 0, (size_t)n * 4, stream);
    hipMemsetAsync(hx, 0, (size_t)n * 96 * 2, stream);   // zero K-padding

    const int NB = (n + 1023) / 1024;    // 98 scan blocks

    w2ext_kernel<<<36, 256, 0, stream>>>(W2, att2, w2t);
    count_kernel<<<(e + 255) / 256, 256, 0, stream>>>(src, dst, deg, e);
    encoder_kernel<<<n / 8, 256, 0, stream>>>(ef, Wq, bq, Wk, bk, Wv, bv, g0, be0,
                                              Wf1, bf1, Wf2, bf2, g1, be1, Wrep, brep,
                                              hx, n);
    xw1_kernel<<<n / 16, 256, 0, stream>>>(x, W1, att1, xw1b, ai1, ajp, n);
    scan1_kernel<<<NB, 1024, 0, stream>>>(deg, bsum, n);
    scan2_kernel<<<1, 128, 0, stream>>>(bsum, NB);
    scan3_kernel<<<NB, 1024, 0, stream>>>(deg, bsum, offs, n);
    scatter_kernel<<<(e + 255) / 256, 256, 0, stream>>>(src, dst, offs, cur, elist, e);
    agg1_kernel<<<n / 4, 256, 0, stream>>>(xw1b, ai1, ajp, att1, b1,
                                           offs, deg, elist, hx, n);
    xw2mfma_kernel<<<(n + 63) / 64, 256, 0, stream>>>(hx, w2t, xw2p, ai2, n);
    agg2_kernel<<<n / 4, 256, 0, stream>>>((const unsigned*)xw2p, ai2, b2,
                                           offs, deg, elist, (float*)d_out, n);
}

// Round 15
// 490.370 us; speedup vs baseline: 1.3991x; 1.0877x over previous
//
#include <hip/hip_runtime.h>
#include <hip/hip_bf16.h>

// N=100000, E=1600000.
// R15: (a) encoder K/V slab back to fp32 (zero unpack VALU ops; encoder was
// 85% VALU-issue-bound at 161us) ; (b) encoder+count+xw1 re-fused into one
// front kernel (now register-compatible: ~60 VGPR max, unlike R5's 128) so
// count/xw1 hide under encoder. xw2 via MFMA GEMM (R14). agg kernels R12.

#define NEG_SLOPE 0.2f

using short8  = __attribute__((ext_vector_type(8))) short;
using floatx4 = __attribute__((ext_vector_type(4))) float;

__device__ __forceinline__ float bf_lo(unsigned u) { return __uint_as_float(u << 16); }
__device__ __forceinline__ float bf_hi(unsigned u) { return __uint_as_float(u & 0xffff0000u); }
__device__ __forceinline__ unsigned pk(float lo, float hi)
{
    __hip_bfloat16 l = __float2bfloat16(lo), h = __float2bfloat16(hi);
    unsigned ul = reinterpret_cast<unsigned short&>(l);
    unsigned uh = reinterpret_cast<unsigned short&>(h);
    return ul | (uh << 16);
}

// ---------------------------------------------------------------------------
// Fused front: blocks [0,EB) encoder | [EB,EB+CB) count | rest xw1.
// Shared memory union: 4352 floats (17.4 KB).
// ---------------------------------------------------------------------------
__global__ void __launch_bounds__(256) front_kernel(
    // encoder
    const float* __restrict__ Xf,
    const float* __restrict__ Wq, const float* __restrict__ bq,
    const float* __restrict__ Wk, const float* __restrict__ bk,
    const float* __restrict__ Wv, const float* __restrict__ bv,
    const float* __restrict__ g0, const float* __restrict__ be0,
    const float* __restrict__ Wf1, const float* __restrict__ bf1,
    const float* __restrict__ Wf2, const float* __restrict__ bf2,
    const float* __restrict__ g1, const float* __restrict__ be1,
    const float* __restrict__ Wrep, const float* __restrict__ brep,
    __hip_bfloat16* __restrict__ hx,
    // count
    const int* __restrict__ src, const int* __restrict__ dst,
    int* __restrict__ deg, int e,
    // xw1
    const float* __restrict__ x, const float* __restrict__ W1,
    const float* __restrict__ att1,
    __hip_bfloat16* __restrict__ xwb,
    float* __restrict__ ai, unsigned* __restrict__ ajp,
    int n, int EB, int CB)
{
    __shared__ float smem[4352];
    int t = threadIdx.x;
    int bid = blockIdx.x;

    if (bid < EB) {
        // ------------------ encoder: 8 nodes/block, fp32 K/V slab ----------
        float* sh = smem;
        size_t base = (size_t)bid * 2560;
#pragma unroll
        for (int i = 0; i < 10; ++i) sh[i * 256 + t] = Xf[base + i * 256 + t];
        __syncthreads();

        int sub = t >> 5;
        int s   = t & 31;
        int v   = bid * 8 + sub;

        float xv[10];
#pragma unroll
        for (int i = 0; i < 10; ++i) xv[i] = sh[sub * 320 + s * 10 + i];
        __syncthreads();   // Xf consumed; slab reused for fp32 K/V

        float q[6], k[6], w[6];
#pragma unroll
        for (int j = 0; j < 6; ++j) { q[j] = bq[j]; k[j] = bk[j]; w[j] = bv[j]; }
#pragma unroll
        for (int i = 0; i < 10; ++i) {
#pragma unroll
            for (int j = 0; j < 6; ++j) {
                q[j] += xv[i] * Wq[i * 6 + j];
                k[j] += xv[i] * Wk[i * 6 + j];
                w[j] += xv[i] * Wv[i * 6 + j];
            }
        }

        // fp32 K/V slab: per node 32 tokens x 16 floats (k0..5 | pad | v0..5 | pad)
        float* kv = sh + sub * 512;
        *(float4*)&kv[s * 16 + 0]  = make_float4(k[0], k[1], k[2], k[3]);
        *(float4*)&kv[s * 16 + 4]  = make_float4(k[4], k[5], 0.f, 0.f);
        *(float4*)&kv[s * 16 + 8]  = make_float4(w[0], w[1], w[2], w[3]);
        *(float4*)&kv[s * 16 + 12] = make_float4(w[4], w[5], 0.f, 0.f);
        __builtin_amdgcn_wave_barrier();

        // logits |.| << 1 -> no max subtraction needed
        const float scale = 0.40824829046386301637f;  // 1/sqrt(6)
        float q0s = q[0] * scale, q1s = q[1] * scale, q2s = q[2] * scale;
        float q3s = q[3] * scale, q4s = q[4] * scale, q5s = q[5] * scale;

        float dA0 = 0.f, dB0 = 0.f, dA1 = 0.f, dB1 = 0.f;
        float aA00 = 0.f, aA01 = 0.f, aA02 = 0.f;
        float aB00 = 0.f, aB01 = 0.f, aB02 = 0.f;
        float aA10 = 0.f, aA11 = 0.f, aA12 = 0.f;
        float aB10 = 0.f, aB11 = 0.f, aB12 = 0.f;

#pragma unroll 4
        for (int t2 = 0; t2 < 32; t2 += 2) {
            float4 ka0 = *(const float4*)&kv[t2 * 16 + 0];
            float4 kb0 = *(const float4*)&kv[t2 * 16 + 4];
            float4 va0 = *(const float4*)&kv[t2 * 16 + 8];
            float4 vb0 = *(const float4*)&kv[t2 * 16 + 12];
            float4 ka1 = *(const float4*)&kv[t2 * 16 + 16];
            float4 kb1 = *(const float4*)&kv[t2 * 16 + 20];
            float4 va1 = *(const float4*)&kv[t2 * 16 + 24];
            float4 vb1 = *(const float4*)&kv[t2 * 16 + 28];
            {
                float p0 = __expf(q0s * ka0.x + q1s * ka0.y + q2s * ka0.z);
                float p1 = __expf(q3s * ka0.w + q4s * kb0.x + q5s * kb0.y);
                dA0 += p0; aA00 += p0 * va0.x; aA01 += p0 * va0.y; aA02 += p0 * va0.z;
                dA1 += p1; aA10 += p1 * va0.w; aA11 += p1 * vb0.x; aA12 += p1 * vb0.y;
            }
            {
                float p0 = __expf(q0s * ka1.x + q1s * ka1.y + q2s * ka1.z);
                float p1 = __expf(q3s * ka1.w + q4s * kb1.x + q5s * kb1.y);
                dB0 += p0; aB00 += p0 * va1.x; aB01 += p0 * va1.y; aB02 += p0 * va1.z;
                dB1 += p1; aB10 += p1 * va1.w; aB11 += p1 * vb1.x; aB12 += p1 * vb1.y;
            }
        }

        float O[6];
        {
            float inv0 = 1.f / (dA0 + dB0);
            float inv1 = 1.f / (dA1 + dB1);
            O[0] = q[0] + (aA00 + aB00) * inv0;
            O[1] = q[1] + (aA01 + aB01) * inv0;
            O[2] = q[2] + (aA02 + aB02) * inv0;
            O[3] = q[3] + (aA10 + aB10) * inv1;
            O[4] = q[4] + (aA11 + aB11) * inv1;
            O[5] = q[5] + (aA12 + aB12) * inv1;
        }

        // LayerNorm(g0, be0)
        {
            float mean = (O[0] + O[1] + O[2] + O[3] + O[4] + O[5]) * (1.f / 6.f);
            float var = 0.f;
#pragma unroll
            for (int j = 0; j < 6; ++j) { float d = O[j] - mean; var += d * d; }
            var *= (1.f / 6.f);
            float r = rsqrtf(var + 1e-5f);
#pragma unroll
            for (int j = 0; j < 6; ++j) O[j] = (O[j] - mean) * r * g0[j] + be0[j];
        }

        // streaming FFN 6->24->6 + residual
        float f[6];
#pragma unroll
        for (int j = 0; j < 6; ++j) f[j] = O[j] + bf2[j];
#pragma unroll 4
        for (int r = 0; r < 24; ++r) {
            float hr = bf1[r];
#pragma unroll
            for (int j = 0; j < 6; ++j) hr += O[j] * Wf1[j * 24 + r];
            hr = fmaxf(hr, 0.f);
#pragma unroll
            for (int j = 0; j < 6; ++j) f[j] += hr * Wf2[r * 6 + j];
        }
        // LayerNorm(g1, be1)
        {
            float mean = (f[0] + f[1] + f[2] + f[3] + f[4] + f[5]) * (1.f / 6.f);
            float var = 0.f;
#pragma unroll
            for (int j = 0; j < 6; ++j) { float d = f[j] - mean; var += d * d; }
            var *= (1.f / 6.f);
            float r = rsqrtf(var + 1e-5f);
#pragma unroll
            for (int j = 0; j < 6; ++j) f[j] = (f[j] - mean) * r * g1[j] + be1[j];
        }

        float wr = Wrep[s];
#pragma unroll
        for (int j = 0; j < 6; ++j) {
            float val = f[j] * wr;
#pragma unroll
            for (int off = 16; off >= 1; off >>= 1) val += __shfl_xor(val, off, 32);
            f[j] = val;
        }
        if (s == 0) {
            float br = brep[0];
#pragma unroll
            for (int j = 0; j < 6; ++j)
                hx[(size_t)v * 96 + 64 + j] = __float2bfloat16(f[j] + br);
        }
    } else if (bid < EB + CB) {
        // ------------------ count: degree histogram ------------------------
        int i = (bid - EB) * 256 + t;
        if (i < e) {
            int ss = src[i], dd = dst[i];
            if (ss != dd) atomicAdd(&deg[dd], 1);
        }
    } else {
        // ------------------ xw1: 16 nodes/block ----------------------------
        float* shW = smem;            // 4096 floats
        float* shX = smem + 4096;     // 256 floats
        int xb = bid - EB - CB;
        int wv = t >> 6, l = t & 63;
#pragma unroll
        for (int i = 0; i < 16; ++i) shW[i * 256 + t] = W1[i * 256 + t];
        int h = l >> 3, c = l & 7;
        float a_i = att1[h * 16 + c];
        float a_j = att1[h * 16 + 8 + c];
        __syncthreads();

#pragma unroll
        for (int it = 0; it < 4; ++it) {
            int v = xb * 16 + it * 4 + wv;
            shX[wv * 64 + l] = x[(size_t)v * 64 + l];
            __builtin_amdgcn_wave_barrier();
            float acc = 0.f;
#pragma unroll
            for (int k4 = 0; k4 < 16; ++k4) {
                float4 xb4 = *(const float4*)&shX[wv * 64 + k4 * 4];
                acc += xb4.x * shW[(k4 * 4 + 0) * 64 + l];
                acc += xb4.y * shW[(k4 * 4 + 1) * 64 + l];
                acc += xb4.z * shW[(k4 * 4 + 2) * 64 + l];
                acc += xb4.w * shW[(k4 * 4 + 3) * 64 + l];
            }
            xwb[(size_t)v * 64 + l] = __float2bfloat16(acc);

            float pi = acc * a_i;
            float pj = acc * a_j;
#pragma unroll
            for (int off = 1; off < 8; off <<= 1) {
                pi += __shfl_xor(pi, off, 64);
                pj += __shfl_xor(pj, off, 64);
            }
            if (c == 0) ai[(size_t)v * 8 + h] = pi;
            float pj_hi = __shfl(pj, (l + 8) & 63, 64);
            if ((l & 15) == 0)
                ajp[(size_t)v * 4 + (h >> 1)] = pk(pj, pj_hi);
            __builtin_amdgcn_wave_barrier();
        }
    }
}

// ---------------------------------------------------------------------------
// CSR build: 3-kernel scan -> scatter
// ---------------------------------------------------------------------------
__global__ void __launch_bounds__(1024) scan1_kernel(
    const int* __restrict__ deg, int* __restrict__ bsum, int n)
{
    __shared__ int sh[1024];
    int t = threadIdx.x;
    int i = blockIdx.x * 1024 + t;
    sh[t] = (i < n) ? deg[i] : 0;
    __syncthreads();
    for (int off = 512; off >= 1; off >>= 1) {
        if (t < off) sh[t] += sh[t + off];
        __syncthreads();
    }
    if (t == 0) bsum[blockIdx.x] = sh[0];
}

__global__ void __launch_bounds__(128) scan2_kernel(int* __restrict__ bsum, int nb)
{
    __shared__ int sh[128];
    int t = threadIdx.x;
    int v = (t < nb) ? bsum[t] : 0;
    sh[t] = v;
    __syncthreads();
    for (int off = 1; off < 128; off <<= 1) {
        int val = (t >= off) ? sh[t - off] : 0;
        __syncthreads();
        sh[t] += val;
        __syncthreads();
    }
    if (t < nb) bsum[t] = sh[t] - v;   // exclusive
}

__global__ void __launch_bounds__(1024) scan3_kernel(
    const int* __restrict__ deg, const int* __restrict__ bsum,
    int* __restrict__ offs, int n)
{
    __shared__ int sh[1024];
    int t = threadIdx.x;
    int i = blockIdx.x * 1024 + t;
    int v = (i < n) ? deg[i] : 0;
    sh[t] = v;
    __syncthreads();
    for (int off = 1; off < 1024; off <<= 1) {
        int val = (t >= off) ? sh[t - off] : 0;
        __syncthreads();
        sh[t] += val;
        __syncthreads();
    }
    if (i < n) offs[i] = bsum[blockIdx.x] + sh[t] - v;
}

__global__ void scatter_kernel(const int* __restrict__ src, const int* __restrict__ dst,
                               const int* __restrict__ offsets, int* __restrict__ cursor,
                               int* __restrict__ elist, int e)
{
    int i = blockIdx.x * blockDim.x + threadIdx.x;
    if (i < e) {
        int s = src[i], d = dst[i];
        if (s != d) {
            int pos = offsets[d] + atomicAdd(&cursor[d], 1);
            elist[pos] = s;
        }
    }
}

// ---------------------------------------------------------------------------
// GAT-1 aggregation, 8-edge chunks, two-phase (R12 structure).
// Output h1 (bf16) into hx rows (stride 96), cols 0..63.
// ---------------------------------------------------------------------------
__global__ void __launch_bounds__(256) agg1_kernel(
    const __hip_bfloat16* __restrict__ xwb, const float* __restrict__ ai1,
    const unsigned* __restrict__ ajp, const float* __restrict__ att1,
    const float* __restrict__ b1,
    const int* __restrict__ offs, const int* __restrict__ deg,
    const int* __restrict__ elist,
    __hip_bfloat16* __restrict__ hx, int n)
{
    int t = threadIdx.x, wv = t >> 6, l = t & 63;
    int v = blockIdx.x * 4 + wv;
    int h = l >> 3, c = l & 7;    // output layout: lane = col l, head h
    int e1 = l >> 3, hp = l & 7;  // phase-1 layout: (edge slot e1, head hp)

    float ai_l = ai1[(size_t)v * 8 + h];
    float ai_p = ai1[(size_t)v * 8 + hp];
    float attj_l = att1[h * 16 + 8 + c];

    // self loop (output layout; butterfly over own row)
    float yself = __bfloat162float(xwb[(size_t)v * 64 + l]);
    float ps = yself * attj_l;
    ps += __shfl_xor(ps, 1, 64);
    ps += __shfl_xor(ps, 2, 64);
    ps += __shfl_xor(ps, 4, 64);
    float a = ai_l + ps;
    a = fmaxf(a, NEG_SLOPE * a);
    float ea  = __expf(a);
    float acc = ea * yself;

    float den_acc = 0.f;   // phase-1 layout
    int off = offs[v], dg = deg[v];
    for (int j = 0; j < dg; j += 8) {
        int idxv = 0;
        if (l < 8 && j + l < dg) idxv = elist[off + j + l];
        // phase 1: weights for 8 edges x 8 heads
        int se = __shfl(idxv, e1, 64);
        unsigned aw = ajp[(size_t)se * 4 + (hp >> 1)];
        float ajv = (hp & 1) ? bf_hi(aw) : bf_lo(aw);
        float u = ai_p + ajv;
        u = fmaxf(u, NEG_SLOPE * u);
        float wl = __expf(u);
        wl = (j + e1 < dg) ? wl : 0.f;
        den_acc += wl;
        // phase 2: gather + apply
#pragma unroll
        for (int b = 0; b < 8; ++b) {
            int s = __shfl(idxv, b, 64);
            float y = __bfloat162float(xwb[(size_t)s * 64 + l]);
            float w = __shfl(wl, b * 8 + h, 64);
            acc += w * y;
        }
    }
    den_acc += __shfl_xor(den_acc, 8, 64);
    den_acc += __shfl_xor(den_acc, 16, 64);
    den_acc += __shfl_xor(den_acc, 32, 64);
    float den = ea + __shfl(den_acc, h, 64);

    float o = acc / den + b1[l];
    o = o > 0.f ? o : expm1f(o);   // elu
    hx[(size_t)v * 96 + l] = __float2bfloat16(o);
}

// ---------------------------------------------------------------------------
// W2extT build: w2t[j][k] (96x96 bf16), j = output col, k = input row.
// cols 0..79 = W2; 80..87 = W2 @ att2_i (per head); 88..95 = W2 @ att2_j.
// ---------------------------------------------------------------------------
__global__ void __launch_bounds__(256) w2ext_kernel(
    const float* __restrict__ W2, const float* __restrict__ att2,
    __hip_bfloat16* __restrict__ w2t)
{
    int idx = blockIdx.x * 256 + threadIdx.x;
    if (idx >= 96 * 96) return;
    int j = idx / 96, k = idx % 96;
    float val = 0.f;
    if (k < 70) {
        if (j < 80) {
            val = W2[k * 80 + j];
        } else if (j < 88) {
            int h = j - 80;
            for (int c = 0; c < 10; ++c)
                val += W2[k * 80 + h * 10 + c] * att2[h * 20 + c];
        } else {
            int h = j - 88;
            for (int c = 0; c < 10; ++c)
                val += W2[k * 80 + h * 10 + c] * att2[h * 20 + 10 + c];
        }
    }
    w2t[j * 96 + k] = __float2bfloat16(val);
}

// ---------------------------------------------------------------------------
// xw2 GEMM via MFMA: D[N x 96] = hx[N x 96] @ W2ext, 16 nodes per wave.
// ---------------------------------------------------------------------------
__global__ void __launch_bounds__(256) xw2mfma_kernel(
    const __hip_bfloat16* __restrict__ hx, const __hip_bfloat16* __restrict__ w2t,
    __hip_bfloat16* __restrict__ xw2p, float* __restrict__ ai2, int n)
{
    int t = threadIdx.x, wv = t >> 6, l = t & 63;
    int base = blockIdx.x * 64 + wv * 16;
    if (base >= n) return;           // per-wave guard; no block barriers here

    int mrow = l & 15;               // A-row within tile / D-col
    int kc   = (l >> 4) * 8;         // k sub-offset (elements)
    int dr0  = (l >> 4) * 4;         // D-row base

    const short* hp = (const short*)hx;
    const short* wp = (const short*)w2t;

    short8 a0 = *(const short8*)(hp + (size_t)(base + mrow) * 96 + 0  + kc);
    short8 a1 = *(const short8*)(hp + (size_t)(base + mrow) * 96 + 32 + kc);
    short8 a2 = *(const short8*)(hp + (size_t)(base + mrow) * 96 + 64 + kc);

#pragma unroll
    for (int nt = 0; nt < 6; ++nt) {
        int col = nt * 16 + mrow;
        short8 b0 = *(const short8*)(wp + (size_t)col * 96 + 0  + kc);
        short8 b1 = *(const short8*)(wp + (size_t)col * 96 + 32 + kc);
        short8 b2 = *(const short8*)(wp + (size_t)col * 96 + 64 + kc);
        floatx4 acc = {0.f, 0.f, 0.f, 0.f};
        acc = __builtin_amdgcn_mfma_f32_16x16x32_bf16(a0, b0, acc, 0, 0, 0);
        acc = __builtin_amdgcn_mfma_f32_16x16x32_bf16(a1, b1, acc, 0, 0, 0);
        acc = __builtin_amdgcn_mfma_f32_16x16x32_bf16(a2, b2, acc, 0, 0, 0);
#pragma unroll
        for (int r = 0; r < 4; ++r) {
            int m = base + dr0 + r;
            float val = acc[r];
            if (nt < 5) {
                xw2p[(size_t)m * 128 + nt * 16 + mrow] = __float2bfloat16(val);
            } else {
                if (mrow < 8) ai2[(size_t)m * 8 + mrow] = val;
                else xw2p[(size_t)m * 128 + 80 + (mrow - 8)] = __float2bfloat16(val);
            }
        }
    }
}

// ---------------------------------------------------------------------------
// GAT-2 aggregation on packed rows, 8-edge chunks, two-phase (unchanged).
// ---------------------------------------------------------------------------
__global__ void __launch_bounds__(256) agg2_kernel(
    const unsigned* __restrict__ xw2p, const float* __restrict__ ai2,
    const float* __restrict__ b2,
    const int* __restrict__ offs, const int* __restrict__ deg,
    const int* __restrict__ elist, float* __restrict__ out, int n)
{
    __shared__ float buf[4][80];
    __shared__ float buf2[4][10];
    int t = threadIdx.x, wv = t >> 6, l = t & 63;
    int v = blockIdx.x * 4 + wv;

    int hc = (l < 40) ? (l / 5) : 0;
    int e1 = l >> 3, hp = l & 7;
    float ai_p = ai2[(size_t)v * 8 + hp];
    float ai_l = (l < 40) ? ai2[(size_t)v * 8 + hc] : 0.f;

    // self loop
    bool act = l < 44;
    unsigned selfw = act ? xw2p[(size_t)v * 64 + l] : 0u;
    int ajl = 40 + (hc >> 1);
    unsigned ajw = __shfl(selfw, ajl, 64);
    float ajs = (hc & 1) ? bf_hi(ajw) : bf_lo(ajw);
    float a = ai_l + ajs;
    a = fmaxf(a, NEG_SLOPE * a);
    float e0 = __expf(a);
    float acc0 = e0 * bf_lo(selfw), acc1 = e0 * bf_hi(selfw);

    float den_acc = 0.f;   // phase-1 layout
    int off = offs[v], dg = deg[v];
    for (int j = 0; j < dg; j += 8) {
        int idxv = 0;
        if (l < 8 && j + l < dg) idxv = elist[off + j + l];
        // phase 1: weights for 8 edges x 8 heads (aj words in-row at 40+h/2)
        int se = __shfl(idxv, e1, 64);
        unsigned aw = xw2p[(size_t)se * 64 + 40 + (hp >> 1)];
        float ajv = (hp & 1) ? bf_hi(aw) : bf_lo(aw);
        float u = ai_p + ajv;
        u = fmaxf(u, NEG_SLOPE * u);
        float wl = __expf(u);
        wl = (j + e1 < dg) ? wl : 0.f;
        den_acc += wl;
        // phase 2
#pragma unroll
        for (int b = 0; b < 8; ++b) {
            int s = __shfl(idxv, b, 64);
            unsigned yw = (l < 40) ? xw2p[(size_t)s * 64 + l] : 0u;
            float w = __shfl(wl, b * 8 + hc, 64);
            acc0 += w * bf_lo(yw);
            acc1 += w * bf_hi(yw);
        }
    }
    den_acc += __shfl_xor(den_acc, 8, 64);
    den_acc += __shfl_xor(den_acc, 16, 64);
    den_acc += __shfl_xor(den_acc, 32, 64);
    float den = e0 + __shfl(den_acc, hc, 64);

    if (l < 40) {
        float inv = 1.f / den;
        buf[wv][2 * l]     = acc0 * inv;
        buf[wv][2 * l + 1] = acc1 * inv;
    }
    __builtin_amdgcn_wave_barrier();
    if (l < 10) {
        float mval = 0.f;
#pragma unroll
        for (int hh = 0; hh < 8; ++hh) mval += buf[wv][hh * 10 + l];
        buf2[wv][l] = mval * 0.125f + b2[l];
    }
    __builtin_amdgcn_wave_barrier();
    if (l < 10) {
        float mx = -1e30f;
#pragma unroll
        for (int cc = 0; cc < 10; ++cc) mx = fmaxf(mx, buf2[wv][cc]);
        float se = 0.f;
#pragma unroll
        for (int cc = 0; cc < 10; ++cc) se += __expf(buf2[wv][cc] - mx);
        out[(size_t)v * 10 + l] = buf2[wv][l] - mx - __logf(se);
    }
}

// ---------------------------------------------------------------------------
extern "C" void kernel_launch(void* const* d_in, const int* in_sizes, int n_in,
                              void* d_out, int out_size, void* d_ws, size_t ws_size,
                              hipStream_t stream)
{
    const float* x    = (const float*)d_in[0];
    const int*   ei   = (const int*)  d_in[1];
    const float* ef   = (const float*)d_in[2];
    const float* W1   = (const float*)d_in[3];
    const float* att1 = (const float*)d_in[4];
    const float* b1   = (const float*)d_in[5];
    const float* W2   = (const float*)d_in[6];
    const float* att2 = (const float*)d_in[7];
    const float* b2   = (const float*)d_in[8];
    const float* Wq   = (const float*)d_in[9];
    const float* bq   = (const float*)d_in[10];
    const float* Wk   = (const float*)d_in[11];
    const float* bk   = (const float*)d_in[12];
    const float* Wv   = (const float*)d_in[13];
    const float* bv   = (const float*)d_in[14];
    const float* g0   = (const float*)d_in[15];
    const float* be0  = (const float*)d_in[16];
    const float* Wf1  = (const float*)d_in[17];
    const float* bf1  = (const float*)d_in[18];
    const float* Wf2  = (const float*)d_in[19];
    const float* bf2  = (const float*)d_in[20];
    const float* g1   = (const float*)d_in[21];
    const float* be1  = (const float*)d_in[22];
    const float* Wrep = (const float*)d_in[23];
    const float* brep = (const float*)d_in[24];

    const int n = in_sizes[0] / 64;   // 100000
    const int e = in_sizes[1] / 2;    // 1600000
    const int* src = ei;
    const int* dst = ei + e;

    char* ws = (char*)d_ws;
    size_t o = 0;
    auto alloc = [&](size_t bytes) -> void* {
        void* p = ws + o;
        o += (bytes + 255) & ~(size_t)255;
        return p;
    };
    __hip_bfloat16* xw1b = (__hip_bfloat16*)alloc((size_t)n * 64 * 2);
    __hip_bfloat16* hx   = (__hip_bfloat16*)alloc((size_t)n * 96 * 2);  // h1|xt|0
    __hip_bfloat16* xw2p = (__hip_bfloat16*)alloc((size_t)n * 128 * 2); // packed
    __hip_bfloat16* w2t  = (__hip_bfloat16*)alloc(96 * 96 * 2);
    unsigned* ajp = (unsigned*)alloc((size_t)n * 4 * 4);  // packed bf16 aj1
    float* ai1   = (float*)alloc((size_t)n * 8 * 4);
    float* ai2   = (float*)alloc((size_t)n * 8 * 4);
    int*   deg   = (int*)  alloc((size_t)n * 4);
    int*   offs  = (int*)  alloc((size_t)n * 4);
    int*   cur   = (int*)  alloc((size_t)n * 4);
    int*   bsum  = (int*)  alloc(256 * 4);
    int*   elist = (int*)  alloc((size_t)e * 4);
    (void)ws_size; (void)n_in; (void)out_size;

    hipMemsetAsync(deg, 0, (size_t)n * 4, stream);
    hipMemsetAsync(cur, 0, (size_t)n * 4, stream);
    hipMemsetAsync(hx, 0, (size_t)n * 96 * 2, stream);   // zero K-padding

    const int NB = (n + 1023) / 1024;    // 98 scan blocks
    const int EB = n / 8;                // 12500 encoder blocks
    const int CB = (e + 255) / 256;      // 6250 count blocks
    const int XB = n / 16;               // 6250 xw1 blocks

    w2ext_kernel<<<36, 256, 0, stream>>>(W2, att2, w2t);
    front_kernel<<<EB + CB + XB, 256, 0, stream>>>(
        ef, Wq, bq, Wk, bk, Wv, bv, g0, be0, Wf1, bf1, Wf2, bf2, g1, be1,
        Wrep, brep, hx,
        src, dst, deg, e,
        x, W1, att1, xw1b, ai1, ajp,
        n, EB, CB);
    scan1_kernel<<<NB, 1024, 0, stream>>>(deg, bsum, n);
    scan2_kernel<<<1, 128, 0, stream>>>(bsum, NB);
    scan3_kernel<<<NB, 1024, 0, stream>>>(deg, bsum, offs, n);
    scatter_kernel<<<(e + 255) / 256, 256, 0, stream>>>(src, dst, offs, cur, elist, e);
    agg1_kernel<<<n / 4, 256, 0, stream>>>(xw1b, ai1, ajp, att1, b1,
                                           offs, deg, elist, hx, n);
    xw2mfma_kernel<<<(n + 63) / 64, 256, 0, stream>>>(hx, w2t, xw2p, ai2, n);
    agg2_kernel<<<n / 4, 256, 0, stream>>>((const unsigned*)xw2p, ai2, b2,
                                           offs, deg, elist, (float*)d_out, n);
}

// Round 16
// 411.845 us; speedup vs baseline: 1.6659x; 1.1907x over previous
//
#include <hip/hip_runtime.h>
#include <hip/hip_bf16.h>

// N=100000, E=1600000.
// R16: (a) encoder K/V slab = 12 fp32/token (3 ds_read_b128, 0 unpacks,
// 4-way write conflicts instead of 16-way); (b) scatter made atomic-free
// (count records per-edge rank). Rest = R15 structure.

#define NEG_SLOPE 0.2f

using short8  = __attribute__((ext_vector_type(8))) short;
using floatx4 = __attribute__((ext_vector_type(4))) float;

__device__ __forceinline__ float bf_lo(unsigned u) { return __uint_as_float(u << 16); }
__device__ __forceinline__ float bf_hi(unsigned u) { return __uint_as_float(u & 0xffff0000u); }
__device__ __forceinline__ unsigned pk(float lo, float hi)
{
    __hip_bfloat16 l = __float2bfloat16(lo), h = __float2bfloat16(hi);
    unsigned ul = reinterpret_cast<unsigned short&>(l);
    unsigned uh = reinterpret_cast<unsigned short&>(h);
    return ul | (uh << 16);
}

// ---------------------------------------------------------------------------
// Fused front: blocks [0,EB) encoder | [EB,EB+CB) count | rest xw1.
// ---------------------------------------------------------------------------
__global__ void __launch_bounds__(256) front_kernel(
    // encoder
    const float* __restrict__ Xf,
    const float* __restrict__ Wq, const float* __restrict__ bq,
    const float* __restrict__ Wk, const float* __restrict__ bk,
    const float* __restrict__ Wv, const float* __restrict__ bv,
    const float* __restrict__ g0, const float* __restrict__ be0,
    const float* __restrict__ Wf1, const float* __restrict__ bf1,
    const float* __restrict__ Wf2, const float* __restrict__ bf2,
    const float* __restrict__ g1, const float* __restrict__ be1,
    const float* __restrict__ Wrep, const float* __restrict__ brep,
    __hip_bfloat16* __restrict__ hx,
    // count
    const int* __restrict__ src, const int* __restrict__ dst,
    int* __restrict__ deg, int* __restrict__ rank, int e,
    // xw1
    const float* __restrict__ x, const float* __restrict__ W1,
    const float* __restrict__ att1,
    __hip_bfloat16* __restrict__ xwb,
    float* __restrict__ ai, unsigned* __restrict__ ajp,
    int n, int EB, int CB)
{
    __shared__ float smem[4352];
    int t = threadIdx.x;
    int bid = blockIdx.x;

    if (bid < EB) {
        // ------------------ encoder: 8 nodes/block, 12-fp32 K/V slab -------
        float* sh = smem;
        size_t base = (size_t)bid * 2560;
#pragma unroll
        for (int i = 0; i < 10; ++i) sh[i * 256 + t] = Xf[base + i * 256 + t];
        __syncthreads();

        int sub = t >> 5;
        int s   = t & 31;
        int v   = bid * 8 + sub;

        float xv[10];
#pragma unroll
        for (int i = 0; i < 10; ++i) xv[i] = sh[sub * 320 + s * 10 + i];
        __syncthreads();   // Xf consumed; slab reused for K/V

        float q[6], k[6], w[6];
#pragma unroll
        for (int j = 0; j < 6; ++j) { q[j] = bq[j]; k[j] = bk[j]; w[j] = bv[j]; }
#pragma unroll
        for (int i = 0; i < 10; ++i) {
#pragma unroll
            for (int j = 0; j < 6; ++j) {
                q[j] += xv[i] * Wq[i * 6 + j];
                k[j] += xv[i] * Wk[i * 6 + j];
                w[j] += xv[i] * Wv[i * 6 + j];
            }
        }

        // K/V slab: 12 floats/token: [k0..k3][k4,k5,v0,v1][v2..v5]
        float* kv = sh + sub * 384;
        *(float4*)&kv[s * 12 + 0] = make_float4(k[0], k[1], k[2], k[3]);
        *(float4*)&kv[s * 12 + 4] = make_float4(k[4], k[5], w[0], w[1]);
        *(float4*)&kv[s * 12 + 8] = make_float4(w[2], w[3], w[4], w[5]);
        __builtin_amdgcn_wave_barrier();

        // logits |.| << 1 -> no max subtraction needed
        const float scale = 0.40824829046386301637f;  // 1/sqrt(6)
        float q0s = q[0] * scale, q1s = q[1] * scale, q2s = q[2] * scale;
        float q3s = q[3] * scale, q4s = q[4] * scale, q5s = q[5] * scale;

        float dA0 = 0.f, dB0 = 0.f, dA1 = 0.f, dB1 = 0.f;
        float aA00 = 0.f, aA01 = 0.f, aA02 = 0.f;
        float aB00 = 0.f, aB01 = 0.f, aB02 = 0.f;
        float aA10 = 0.f, aA11 = 0.f, aA12 = 0.f;
        float aB10 = 0.f, aB11 = 0.f, aB12 = 0.f;

#pragma unroll 4
        for (int t2 = 0; t2 < 32; t2 += 2) {
            float4 A0 = *(const float4*)&kv[t2 * 12 + 0];
            float4 A1 = *(const float4*)&kv[t2 * 12 + 4];
            float4 A2 = *(const float4*)&kv[t2 * 12 + 8];
            float4 B0 = *(const float4*)&kv[t2 * 12 + 12];
            float4 B1 = *(const float4*)&kv[t2 * 12 + 16];
            float4 B2 = *(const float4*)&kv[t2 * 12 + 20];
            {
                float p0 = __expf(q0s * A0.x + q1s * A0.y + q2s * A0.z);
                float p1 = __expf(q3s * A0.w + q4s * A1.x + q5s * A1.y);
                dA0 += p0; aA00 += p0 * A1.z; aA01 += p0 * A1.w; aA02 += p0 * A2.x;
                dA1 += p1; aA10 += p1 * A2.y; aA11 += p1 * A2.z; aA12 += p1 * A2.w;
            }
            {
                float p0 = __expf(q0s * B0.x + q1s * B0.y + q2s * B0.z);
                float p1 = __expf(q3s * B0.w + q4s * B1.x + q5s * B1.y);
                dB0 += p0; aB00 += p0 * B1.z; aB01 += p0 * B1.w; aB02 += p0 * B2.x;
                dB1 += p1; aB10 += p1 * B2.y; aB11 += p1 * B2.z; aB12 += p1 * B2.w;
            }
        }

        float O[6];
        {
            float inv0 = 1.f / (dA0 + dB0);
            float inv1 = 1.f / (dA1 + dB1);
            O[0] = q[0] + (aA00 + aB00) * inv0;
            O[1] = q[1] + (aA01 + aB01) * inv0;
            O[2] = q[2] + (aA02 + aB02) * inv0;
            O[3] = q[3] + (aA10 + aB10) * inv1;
            O[4] = q[4] + (aA11 + aB11) * inv1;
            O[5] = q[5] + (aA12 + aB12) * inv1;
        }

        // LayerNorm(g0, be0)
        {
            float mean = (O[0] + O[1] + O[2] + O[3] + O[4] + O[5]) * (1.f / 6.f);
            float var = 0.f;
#pragma unroll
            for (int j = 0; j < 6; ++j) { float d = O[j] - mean; var += d * d; }
            var *= (1.f / 6.f);
            float r = rsqrtf(var + 1e-5f);
#pragma unroll
            for (int j = 0; j < 6; ++j) O[j] = (O[j] - mean) * r * g0[j] + be0[j];
        }

        // streaming FFN 6->24->6 + residual
        float f[6];
#pragma unroll
        for (int j = 0; j < 6; ++j) f[j] = O[j] + bf2[j];
#pragma unroll 4
        for (int r = 0; r < 24; ++r) {
            float hr = bf1[r];
#pragma unroll
            for (int j = 0; j < 6; ++j) hr += O[j] * Wf1[j * 24 + r];
            hr = fmaxf(hr, 0.f);
#pragma unroll
            for (int j = 0; j < 6; ++j) f[j] += hr * Wf2[r * 6 + j];
        }
        // LayerNorm(g1, be1)
        {
            float mean = (f[0] + f[1] + f[2] + f[3] + f[4] + f[5]) * (1.f / 6.f);
            float var = 0.f;
#pragma unroll
            for (int j = 0; j < 6; ++j) { float d = f[j] - mean; var += d * d; }
            var *= (1.f / 6.f);
            float r = rsqrtf(var + 1e-5f);
#pragma unroll
            for (int j = 0; j < 6; ++j) f[j] = (f[j] - mean) * r * g1[j] + be1[j];
        }

        float wr = Wrep[s];
#pragma unroll
        for (int j = 0; j < 6; ++j) {
            float val = f[j] * wr;
#pragma unroll
            for (int off = 16; off >= 1; off >>= 1) val += __shfl_xor(val, off, 32);
            f[j] = val;
        }
        if (s == 0) {
            float br = brep[0];
#pragma unroll
            for (int j = 0; j < 6; ++j)
                hx[(size_t)v * 96 + 64 + j] = __float2bfloat16(f[j] + br);
        }
    } else if (bid < EB + CB) {
        // ------------------ count: degree histogram + per-edge rank --------
        int i = (bid - EB) * 256 + t;
        if (i < e) {
            int ss = src[i], dd = dst[i];
            if (ss != dd) rank[i] = atomicAdd(&deg[dd], 1);
        }
    } else {
        // ------------------ xw1: 16 nodes/block ----------------------------
        float* shW = smem;            // 4096 floats
        float* shX = smem + 4096;     // 256 floats
        int xb = bid - EB - CB;
        int wv = t >> 6, l = t & 63;
#pragma unroll
        for (int i = 0; i < 16; ++i) shW[i * 256 + t] = W1[i * 256 + t];
        int h = l >> 3, c = l & 7;
        float a_i = att1[h * 16 + c];
        float a_j = att1[h * 16 + 8 + c];
        __syncthreads();

#pragma unroll
        for (int it = 0; it < 4; ++it) {
            int v = xb * 16 + it * 4 + wv;
            shX[wv * 64 + l] = x[(size_t)v * 64 + l];
            __builtin_amdgcn_wave_barrier();
            float acc = 0.f;
#pragma unroll
            for (int k4 = 0; k4 < 16; ++k4) {
                float4 xb4 = *(const float4*)&shX[wv * 64 + k4 * 4];
                acc += xb4.x * shW[(k4 * 4 + 0) * 64 + l];
                acc += xb4.y * shW[(k4 * 4 + 1) * 64 + l];
                acc += xb4.z * shW[(k4 * 4 + 2) * 64 + l];
                acc += xb4.w * shW[(k4 * 4 + 3) * 64 + l];
            }
            xwb[(size_t)v * 64 + l] = __float2bfloat16(acc);

            float pi = acc * a_i;
            float pj = acc * a_j;
#pragma unroll
            for (int off = 1; off < 8; off <<= 1) {
                pi += __shfl_xor(pi, off, 64);
                pj += __shfl_xor(pj, off, 64);
            }
            if (c == 0) ai[(size_t)v * 8 + h] = pi;
            float pj_hi = __shfl(pj, (l + 8) & 63, 64);
            if ((l & 15) == 0)
                ajp[(size_t)v * 4 + (h >> 1)] = pk(pj, pj_hi);
            __builtin_amdgcn_wave_barrier();
        }
    }
}

// ---------------------------------------------------------------------------
// CSR build: 3-kernel scan -> atomic-free scatter
// ---------------------------------------------------------------------------
__global__ void __launch_bounds__(1024) scan1_kernel(
    const int* __restrict__ deg, int* __restrict__ bsum, int n)
{
    __shared__ int sh[1024];
    int t = threadIdx.x;
    int i = blockIdx.x * 1024 + t;
    sh[t] = (i < n) ? deg[i] : 0;
    __syncthreads();
    for (int off = 512; off >= 1; off >>= 1) {
        if (t < off) sh[t] += sh[t + off];
        __syncthreads();
    }
    if (t == 0) bsum[blockIdx.x] = sh[0];
}

__global__ void __launch_bounds__(128) scan2_kernel(int* __restrict__ bsum, int nb)
{
    __shared__ int sh[128];
    int t = threadIdx.x;
    int v = (t < nb) ? bsum[t] : 0;
    sh[t] = v;
    __syncthreads();
    for (int off = 1; off < 128; off <<= 1) {
        int val = (t >= off) ? sh[t - off] : 0;
        __syncthreads();
        sh[t] += val;
        __syncthreads();
    }
    if (t < nb) bsum[t] = sh[t] - v;   // exclusive
}

__global__ void __launch_bounds__(1024) scan3_kernel(
    const int* __restrict__ deg, const int* __restrict__ bsum,
    int* __restrict__ offs, int n)
{
    __shared__ int sh[1024];
    int t = threadIdx.x;
    int i = blockIdx.x * 1024 + t;
    int v = (i < n) ? deg[i] : 0;
    sh[t] = v;
    __syncthreads();
    for (int off = 1; off < 1024; off <<= 1) {
        int val = (t >= off) ? sh[t - off] : 0;
        __syncthreads();
        sh[t] += val;
        __syncthreads();
    }
    if (i < n) offs[i] = bsum[blockIdx.x] + sh[t] - v;
}

__global__ void scatter_kernel(const int* __restrict__ src, const int* __restrict__ dst,
                               const int* __restrict__ offsets,
                               const int* __restrict__ rank,
                               int* __restrict__ elist, int e)
{
    int i = blockIdx.x * blockDim.x + threadIdx.x;
    if (i < e) {
        int s = src[i], d = dst[i];
        if (s != d) elist[offsets[d] + rank[i]] = s;
    }
}

// ---------------------------------------------------------------------------
// GAT-1 aggregation, 8-edge chunks, two-phase (R12 structure).
// Output h1 (bf16) into hx rows (stride 96), cols 0..63.
// ---------------------------------------------------------------------------
__global__ void __launch_bounds__(256) agg1_kernel(
    const __hip_bfloat16* __restrict__ xwb, const float* __restrict__ ai1,
    const unsigned* __restrict__ ajp, const float* __restrict__ att1,
    const float* __restrict__ b1,
    const int* __restrict__ offs, const int* __restrict__ deg,
    const int* __restrict__ elist,
    __hip_bfloat16* __restrict__ hx, int n)
{
    int t = threadIdx.x, wv = t >> 6, l = t & 63;
    int v = blockIdx.x * 4 + wv;
    int h = l >> 3, c = l & 7;    // output layout: lane = col l, head h
    int e1 = l >> 3, hp = l & 7;  // phase-1 layout: (edge slot e1, head hp)

    float ai_l = ai1[(size_t)v * 8 + h];
    float ai_p = ai1[(size_t)v * 8 + hp];
    float attj_l = att1[h * 16 + 8 + c];

    // self loop (output layout; butterfly over own row)
    float yself = __bfloat162float(xwb[(size_t)v * 64 + l]);
    float ps = yself * attj_l;
    ps += __shfl_xor(ps, 1, 64);
    ps += __shfl_xor(ps, 2, 64);
    ps += __shfl_xor(ps, 4, 64);
    float a = ai_l + ps;
    a = fmaxf(a, NEG_SLOPE * a);
    float ea  = __expf(a);
    float acc = ea * yself;

    float den_acc = 0.f;   // phase-1 layout
    int off = offs[v], dg = deg[v];
    for (int j = 0; j < dg; j += 8) {
        int idxv = 0;
        if (l < 8 && j + l < dg) idxv = elist[off + j + l];
        // phase 1: weights for 8 edges x 8 heads
        int se = __shfl(idxv, e1, 64);
        unsigned aw = ajp[(size_t)se * 4 + (hp >> 1)];
        float ajv = (hp & 1) ? bf_hi(aw) : bf_lo(aw);
        float u = ai_p + ajv;
        u = fmaxf(u, NEG_SLOPE * u);
        float wl = __expf(u);
        wl = (j + e1 < dg) ? wl : 0.f;
        den_acc += wl;
        // phase 2: gather + apply
#pragma unroll
        for (int b = 0; b < 8; ++b) {
            int s = __shfl(idxv, b, 64);
            float y = __bfloat162float(xwb[(size_t)s * 64 + l]);
            float w = __shfl(wl, b * 8 + h, 64);
            acc += w * y;
        }
    }
    den_acc += __shfl_xor(den_acc, 8, 64);
    den_acc += __shfl_xor(den_acc, 16, 64);
    den_acc += __shfl_xor(den_acc, 32, 64);
    float den = ea + __shfl(den_acc, h, 64);

    float o = acc / den + b1[l];
    o = o > 0.f ? o : expm1f(o);   // elu
    hx[(size_t)v * 96 + l] = __float2bfloat16(o);
}

// ---------------------------------------------------------------------------
// W2extT build: w2t[j][k] (96x96 bf16), j = output col, k = input row.
// ---------------------------------------------------------------------------
__global__ void __launch_bounds__(256) w2ext_kernel(
    const float* __restrict__ W2, const float* __restrict__ att2,
    __hip_bfloat16* __restrict__ w2t)
{
    int idx = blockIdx.x * 256 + threadIdx.x;
    if (idx >= 96 * 96) return;
    int j = idx / 96, k = idx % 96;
    float val = 0.f;
    if (k < 70) {
        if (j < 80) {
            val = W2[k * 80 + j];
        } else if (j < 88) {
            int h = j - 80;
            for (int c = 0; c < 10; ++c)
                val += W2[k * 80 + h * 10 + c] * att2[h * 20 + c];
        } else {
            int h = j - 88;
            for (int c = 0; c < 10; ++c)
                val += W2[k * 80 + h * 10 + c] * att2[h * 20 + 10 + c];
        }
    }
    w2t[j * 96 + k] = __float2bfloat16(val);
}

// ---------------------------------------------------------------------------
// xw2 GEMM via MFMA: D[N x 96] = hx[N x 96] @ W2ext, 16 nodes per wave.
// ---------------------------------------------------------------------------
__global__ void __launch_bounds__(256) xw2mfma_kernel(
    const __hip_bfloat16* __restrict__ hx, const __hip_bfloat16* __restrict__ w2t,
    __hip_bfloat16* __restrict__ xw2p, float* __restrict__ ai2, int n)
{
    int t = threadIdx.x, wv = t >> 6, l = t & 63;
    int base = blockIdx.x * 64 + wv * 16;
    if (base >= n) return;

    int mrow = l & 15;
    int kc   = (l >> 4) * 8;
    int dr0  = (l >> 4) * 4;

    const short* hp = (const short*)hx;
    const short* wp = (const short*)w2t;

    short8 a0 = *(const short8*)(hp + (size_t)(base + mrow) * 96 + 0  + kc);
    short8 a1 = *(const short8*)(hp + (size_t)(base + mrow) * 96 + 32 + kc);
    short8 a2 = *(const short8*)(hp + (size_t)(base + mrow) * 96 + 64 + kc);

#pragma unroll
    for (int nt = 0; nt < 6; ++nt) {
        int col = nt * 16 + mrow;
        short8 b0 = *(const short8*)(wp + (size_t)col * 96 + 0  + kc);
        short8 b1 = *(const short8*)(wp + (size_t)col * 96 + 32 + kc);
        short8 b2 = *(const short8*)(wp + (size_t)col * 96 + 64 + kc);
        floatx4 acc = {0.f, 0.f, 0.f, 0.f};
        acc = __builtin_amdgcn_mfma_f32_16x16x32_bf16(a0, b0, acc, 0, 0, 0);
        acc = __builtin_amdgcn_mfma_f32_16x16x32_bf16(a1, b1, acc, 0, 0, 0);
        acc = __builtin_amdgcn_mfma_f32_16x16x32_bf16(a2, b2, acc, 0, 0, 0);
#pragma unroll
        for (int r = 0; r < 4; ++r) {
            int m = base + dr0 + r;
            float val = acc[r];
            if (nt < 5) {
                xw2p[(size_t)m * 128 + nt * 16 + mrow] = __float2bfloat16(val);
            } else {
                if (mrow < 8) ai2[(size_t)m * 8 + mrow] = val;
                else xw2p[(size_t)m * 128 + 80 + (mrow - 8)] = __float2bfloat16(val);
            }
        }
    }
}

// ---------------------------------------------------------------------------
// GAT-2 aggregation on packed rows, 8-edge chunks, two-phase (unchanged).
// ---------------------------------------------------------------------------
__global__ void __launch_bounds__(256) agg2_kernel(
    const unsigned* __restrict__ xw2p, const float* __restrict__ ai2,
    const float* __restrict__ b2,
    const int* __restrict__ offs, const int* __restrict__ deg,
    const int* __restrict__ elist, float* __restrict__ out, int n)
{
    __shared__ float buf[4][80];
    __shared__ float buf2[4][10];
    int t = threadIdx.x, wv = t >> 6, l = t & 63;
    int v = blockIdx.x * 4 + wv;

    int hc = (l < 40) ? (l / 5) : 0;
    int e1 = l >> 3, hp = l & 7;
    float ai_p = ai2[(size_t)v * 8 + hp];
    float ai_l = (l < 40) ? ai2[(size_t)v * 8 + hc] : 0.f;

    // self loop
    bool act = l < 44;
    unsigned selfw = act ? xw2p[(size_t)v * 64 + l] : 0u;
    int ajl = 40 + (hc >> 1);
    unsigned ajw = __shfl(selfw, ajl, 64);
    float ajs = (hc & 1) ? bf_hi(ajw) : bf_lo(ajw);
    float a = ai_l + ajs;
    a = fmaxf(a, NEG_SLOPE * a);
    float e0 = __expf(a);
    float acc0 = e0 * bf_lo(selfw), acc1 = e0 * bf_hi(selfw);

    float den_acc = 0.f;   // phase-1 layout
    int off = offs[v], dg = deg[v];
    for (int j = 0; j < dg; j += 8) {
        int idxv = 0;
        if (l < 8 && j + l < dg) idxv = elist[off + j + l];
        // phase 1: weights for 8 edges x 8 heads (aj words in-row at 40+h/2)
        int se = __shfl(idxv, e1, 64);
        unsigned aw = xw2p[(size_t)se * 64 + 40 + (hp >> 1)];
        float ajv = (hp & 1) ? bf_hi(aw) : bf_lo(aw);
        float u = ai_p + ajv;
        u = fmaxf(u, NEG_SLOPE * u);
        float wl = __expf(u);
        wl = (j + e1 < dg) ? wl : 0.f;
        den_acc += wl;
        // phase 2
#pragma unroll
        for (int b = 0; b < 8; ++b) {
            int s = __shfl(idxv, b, 64);
            unsigned yw = (l < 40) ? xw2p[(size_t)s * 64 + l] : 0u;
            float w = __shfl(wl, b * 8 + hc, 64);
            acc0 += w * bf_lo(yw);
            acc1 += w * bf_hi(yw);
        }
    }
    den_acc += __shfl_xor(den_acc, 8, 64);
    den_acc += __shfl_xor(den_acc, 16, 64);
    den_acc += __shfl_xor(den_acc, 32, 64);
    float den = e0 + __shfl(den_acc, hc, 64);

    if (l < 40) {
        float inv = 1.f / den;
        buf[wv][2 * l]     = acc0 * inv;
        buf[wv][2 * l + 1] = acc1 * inv;
    }
    __builtin_amdgcn_wave_barrier();
    if (l < 10) {
        float mval = 0.f;
#pragma unroll
        for (int hh = 0; hh < 8; ++hh) mval += buf[wv][hh * 10 + l];
        buf2[wv][l] = mval * 0.125f + b2[l];
    }
    __builtin_amdgcn_wave_barrier();
    if (l < 10) {
        float mx = -1e30f;
#pragma unroll
        for (int cc = 0; cc < 10; ++cc) mx = fmaxf(mx, buf2[wv][cc]);
        float se = 0.f;
#pragma unroll
        for (int cc = 0; cc < 10; ++cc) se += __expf(buf2[wv][cc] - mx);
        out[(size_t)v * 10 + l] = buf2[wv][l] - mx - __logf(se);
    }
}

// ---------------------------------------------------------------------------
extern "C" void kernel_launch(void* const* d_in, const int* in_sizes, int n_in,
                              void* d_out, int out_size, void* d_ws, size_t ws_size,
                              hipStream_t stream)
{
    const float* x    = (const float*)d_in[0];
    const int*   ei   = (const int*)  d_in[1];
    const float* ef   = (const float*)d_in[2];
    const float* W1   = (const float*)d_in[3];
    const float* att1 = (const float*)d_in[4];
    const float* b1   = (const float*)d_in[5];
    const float* W2   = (const float*)d_in[6];
    const float* att2 = (const float*)d_in[7];
    const float* b2   = (const float*)d_in[8];
    const float* Wq   = (const float*)d_in[9];
    const float* bq   = (const float*)d_in[10];
    const float* Wk   = (const float*)d_in[11];
    const float* bk   = (const float*)d_in[12];
    const float* Wv   = (const float*)d_in[13];
    const float* bv   = (const float*)d_in[14];
    const float* g0   = (const float*)d_in[15];
    const float* be0  = (const float*)d_in[16];
    const float* Wf1  = (const float*)d_in[17];
    const float* bf1  = (const float*)d_in[18];
    const float* Wf2  = (const float*)d_in[19];
    const float* bf2  = (const float*)d_in[20];
    const float* g1   = (const float*)d_in[21];
    const float* be1  = (const float*)d_in[22];
    const float* Wrep = (const float*)d_in[23];
    const float* brep = (const float*)d_in[24];

    const int n = in_sizes[0] / 64;   // 100000
    const int e = in_sizes[1] / 2;    // 1600000
    const int* src = ei;
    const int* dst = ei + e;

    char* ws = (char*)d_ws;
    size_t o = 0;
    auto alloc = [&](size_t bytes) -> void* {
        void* p = ws + o;
        o += (bytes + 255) & ~(size_t)255;
        return p;
    };
    __hip_bfloat16* xw1b = (__hip_bfloat16*)alloc((size_t)n * 64 * 2);
    __hip_bfloat16* hx   = (__hip_bfloat16*)alloc((size_t)n * 96 * 2);  // h1|xt|0
    __hip_bfloat16* xw2p = (__hip_bfloat16*)alloc((size_t)n * 128 * 2); // packed
    __hip_bfloat16* w2t  = (__hip_bfloat16*)alloc(96 * 96 * 2);
    unsigned* ajp = (unsigned*)alloc((size_t)n * 4 * 4);  // packed bf16 aj1
    float* ai1   = (float*)alloc((size_t)n * 8 * 4);
    float* ai2   = (float*)alloc((size_t)n * 8 * 4);
    int*   deg   = (int*)  alloc((size_t)n * 4);
    int*   offs  = (int*)  alloc((size_t)n * 4);
    int*   rank  = (int*)  alloc((size_t)e * 4);
    int*   bsum  = (int*)  alloc(256 * 4);
    int*   elist = (int*)  alloc((size_t)e * 4);
    (void)ws_size; (void)n_in; (void)out_size;

    hipMemsetAsync(deg, 0, (size_t)n * 4, stream);
    hipMemsetAsync(hx, 0, (size_t)n * 96 * 2, stream);   // zero K-padding

    const int NB = (n + 1023) / 1024;    // 98 scan blocks
    const int EB = n / 8;                // 12500 encoder blocks
    const int CB = (e + 255) / 256;      // 6250 count blocks
    const int XB = n / 16;               // 6250 xw1 blocks

    w2ext_kernel<<<36, 256, 0, stream>>>(W2, att2, w2t);
    front_kernel<<<EB + CB + XB, 256, 0, stream>>>(
        ef, Wq, bq, Wk, bk, Wv, bv, g0, be0, Wf1, bf1, Wf2, bf2, g1, be1,
        Wrep, brep, hx,
        src, dst, deg, rank, e,
        x, W1, att1, xw1b, ai1, ajp,
        n, EB, CB);
    scan1_kernel<<<NB, 1024, 0, stream>>>(deg, bsum, n);
    scan2_kernel<<<1, 128, 0, stream>>>(bsum, NB);
    scan3_kernel<<<NB, 1024, 0, stream>>>(deg, bsum, offs, n);
    scatter_kernel<<<(e + 255) / 256, 256, 0, stream>>>(src, dst, offs, rank,
                                                        elist, e);
    agg1_kernel<<<n / 4, 256, 0, stream>>>(xw1b, ai1, ajp, att1, b1,
                                           offs, deg, elist, hx, n);
    xw2mfma_kernel<<<(n + 63) / 64, 256, 0, stream>>>(hx, w2t, xw2p, ai2, n);
    agg2_kernel<<<n / 4, 256, 0, stream>>>((const unsigned*)xw2p, ai2, b2,
                                           offs, deg, elist, (float*)d_out, n);
}